// Round 4
// baseline (337.037 us; speedup 1.0000x reference)
//
#include <hip/hip_runtime.h>
#include <type_traits>

#define D_MODEL 1024
#define NHEADS 16
#define DHEAD 64
#define SEQ 2048
#define BATCH 2
#define MROWS (BATCH*SEQ)   // 4096

typedef unsigned short ushort_t;
using bf16x8 = __attribute__((ext_vector_type(8))) __bf16;
using us4    = __attribute__((ext_vector_type(4))) unsigned short;
using us8    = __attribute__((ext_vector_type(8))) unsigned short;
using f32x4  = __attribute__((ext_vector_type(4))) float;

__device__ __forceinline__ ushort_t f2bf(float f) {
    unsigned int u = __builtin_bit_cast(unsigned int, f);
    u += 0x7FFFu + ((u >> 16) & 1u);
    return (ushort_t)(u >> 16);
}

// ---------------------------------------------------------------------------
// Convert fp32 inputs -> canonical bf16: x (4M) + Wq/Wk/Wv/Wo (1M each) = 8M.
// ---------------------------------------------------------------------------
__global__ __launch_bounds__(256) void cvt_kernel(
    const float* __restrict__ x,
    const float* __restrict__ wq, const float* __restrict__ wk,
    const float* __restrict__ wv, const float* __restrict__ wo,
    ushort_t* __restrict__ xb,
    ushort_t* __restrict__ wqb, ushort_t* __restrict__ wkb,
    ushort_t* __restrict__ wvb, ushort_t* __restrict__ wob)
{
    const size_t XN = (size_t)MROWS * D_MODEL;          // 4 Mi
    const size_t WN = (size_t)D_MODEL * D_MODEL;        // 1 Mi
    size_t i = ((size_t)blockIdx.x * 256 + threadIdx.x) * 4;
    const float* s; ushort_t* d; size_t off;
    if (i < XN) { s = x; d = xb; off = i; }
    else {
        size_t j = i - XN;
        int w = (int)(j / WN);
        off = j - (size_t)w * WN;
        s = (w == 0) ? wq : (w == 1) ? wk : (w == 2) ? wv : wo;
        d = (w == 0) ? wqb : (w == 1) ? wkb : (w == 2) ? wvb : wob;
    }
    const f32x4 v = *(const f32x4*)(s + off);
    us4 o;
    #pragma unroll
    for (int t = 0; t < 4; ++t) o[t] = f2bf(v[t]);
    *(us4*)(d + off) = o;
}

// ---------------------------------------------------------------------------
// NT GEMM: Y[M,1024] = A[M,1024] @ W[1024,1024]^T + bias (+ residual, fp32)
// 64x64 tile per block, 4 waves (2x2), each wave 32x32 via 2x2 mfma 16x16x32.
// grid.z selects among 3 weight sets (QKV fused launch).
// ---------------------------------------------------------------------------
template<typename OutT, bool RES>
__global__ __launch_bounds__(256) void gemm_nt(
    const ushort_t* __restrict__ A,
    const ushort_t* __restrict__ W0, const ushort_t* __restrict__ W1, const ushort_t* __restrict__ W2,
    const float* __restrict__ b0, const float* __restrict__ b1, const float* __restrict__ b2,
    const float* __restrict__ res,
    OutT* __restrict__ Y0, OutT* __restrict__ Y1, OutT* __restrict__ Y2)
{
    constexpr int K  = D_MODEL;
    constexpr int BK = 32;
    constexpr int LDP = BK + 8;   // pad: 40 bf16 = 80B rows, keeps 16B alignment
    __shared__ ushort_t As[64 * LDP];
    __shared__ ushort_t Ws[64 * LDP];

    const int z = blockIdx.z;
    const ushort_t* W  = (z == 0) ? W0 : (z == 1) ? W1 : W2;
    const float* bias  = (z == 0) ? b0 : (z == 1) ? b1 : b2;
    OutT* Y            = (z == 0) ? Y0 : (z == 1) ? Y1 : Y2;

    const int i0 = blockIdx.x * 64;
    const int j0 = blockIdx.y * 64;
    const int tid  = threadIdx.x;
    const int lane = tid & 63;
    const int w    = tid >> 6;
    const int wm   = (w >> 1) * 32;
    const int wn   = (w & 1) * 32;
    const int l15  = lane & 15;
    const int quad = lane >> 4;

    const int sr = tid >> 2;          // staging row 0..63
    const int sc = (tid & 3) * 8;     // staging col 0,8,16,24
    const ushort_t* gA = A + (size_t)(i0 + sr) * K + sc;
    const ushort_t* gW = W + (size_t)(j0 + sr) * K + sc;

    f32x4 acc[2][2] = {};

    for (int k0 = 0; k0 < K; k0 += BK) {
        *(us8*)&As[sr * LDP + sc] = *(const us8*)(gA + k0);
        *(us8*)&Ws[sr * LDP + sc] = *(const us8*)(gW + k0);
        __syncthreads();
        bf16x8 af[2], bfr[2];
        af[0]  = *(const bf16x8*)&As[(wm      + l15) * LDP + quad * 8];
        af[1]  = *(const bf16x8*)&As[(wm + 16 + l15) * LDP + quad * 8];
        bfr[0] = *(const bf16x8*)&Ws[(wn      + l15) * LDP + quad * 8];
        bfr[1] = *(const bf16x8*)&Ws[(wn + 16 + l15) * LDP + quad * 8];
        #pragma unroll
        for (int t = 0; t < 2; ++t)
            #pragma unroll
            for (int u = 0; u < 2; ++u)
                acc[t][u] = __builtin_amdgcn_mfma_f32_16x16x32_bf16(af[t], bfr[u], acc[t][u], 0, 0, 0);
        __syncthreads();
    }

    #pragma unroll
    for (int u = 0; u < 2; ++u) {
        const int col = j0 + wn + u * 16 + l15;
        const float bv = bias[col];
        #pragma unroll
        for (int t = 0; t < 2; ++t) {
            #pragma unroll
            for (int r = 0; r < 4; ++r) {
                const int row = i0 + wm + t * 16 + quad * 4 + r;
                float v = acc[t][u][r] + bv;
                if constexpr (RES) v += res[(size_t)row * D_MODEL + col];
                if constexpr (std::is_same<OutT, float>::value)
                    Y[(size_t)row * D_MODEL + col] = v;
                else
                    Y[(size_t)row * D_MODEL + col] = f2bf(v);
            }
        }
    }
}

// ---------------------------------------------------------------------------
// Flash attention v2 (causal). Computes S^T = K Q^T so softmax over keys is
// mostly in-lane (16 vals) + 2 shfls. 2 barriers/iter. V prefetch pipelined.
// ---------------------------------------------------------------------------
__global__ __launch_bounds__(256) void attn_kernel(
    const ushort_t* __restrict__ Qg, const ushort_t* __restrict__ Kg,
    const ushort_t* __restrict__ Vg, ushort_t* __restrict__ Og)
{
    constexpr int VP = 72;                 // padded key-pitch
    __shared__ ushort_t Vt[DHEAD * VP];    // [d][key]  (V transposed)
    __shared__ ushort_t Pw[64 * VP];       // [query][key] (wave-private rows)

    const int bh = blockIdx.y;
    const int b = bh >> 4;
    const int h = bh & 15;
    const int qt = gridDim.x - 1 - blockIdx.x;   // heavy blocks dispatch first
    const int q0 = qt * 64;
    const int tid  = threadIdx.x;
    const int lane = tid & 63;
    const int w    = tid >> 6;
    const int l15  = lane & 15;
    const int quad = lane >> 4;

    const size_t headoff = (size_t)h * DHEAD;
    const int qg = q0 + w * 16 + l15;      // this lane's query (as S^T column)

    const size_t qrow = (size_t)(b * SEQ + qg) * D_MODEL + headoff;
    const bf16x8 qf0 = *(const bf16x8*)&Qg[qrow + quad * 8];
    const bf16x8 qf1 = *(const bf16x8*)&Qg[qrow + 32 + quad * 8];

    float m_run = -1e30f, l_run = 0.f;
    f32x4 o[4] = {};   // C-layout: row=query quad*4+r, col=d t*16+l15

    const int nkt = qt + 1;

    // V staging map: thread loads V[key=tid&63][dc*8..+7], dc in {tid>>6, tid>>6+4}
    const int vkey = tid & 63;
    const int dc0  = tid >> 6;         // 0..3
    const int dc1  = dc0 + 4;          // 4..7
    const size_t vbase = (size_t)(b * SEQ) * D_MODEL + headoff;

    // pre-stage V tile 0
    {
        const us8 a = *(const us8*)&Vg[vbase + (size_t)vkey * D_MODEL + dc0 * 8];
        const us8 c = *(const us8*)&Vg[vbase + (size_t)vkey * D_MODEL + dc1 * 8];
        #pragma unroll
        for (int j = 0; j < 8; ++j) {
            Vt[(dc0 * 8 + j) * VP + vkey] = a[j];
            Vt[(dc1 * 8 + j) * VP + vkey] = c[j];
        }
    }
    __syncthreads();

    for (int kt = 0; kt < nkt; ++kt) {
        // issue next V tile's global loads early (latency hidden by this iter)
        const int ktn = (kt + 1 < nkt) ? kt + 1 : kt;
        const us8 vn0 = *(const us8*)&Vg[vbase + (size_t)(ktn * 64 + vkey) * D_MODEL + dc0 * 8];
        const us8 vn1 = *(const us8*)&Vg[vbase + (size_t)(ktn * 64 + vkey) * D_MODEL + dc1 * 8];

        // S^T = K Q^T : rows=64 keys (4 frags), cols=16 queries
        bf16x8 kf0[4], kf1[4];
        #pragma unroll
        for (int f = 0; f < 4; ++f) {
            const size_t krow = (size_t)(b * SEQ + kt * 64 + f * 16 + l15) * D_MODEL + headoff;
            kf0[f] = *(const bf16x8*)&Kg[krow + quad * 8];
            kf1[f] = *(const bf16x8*)&Kg[krow + 32 + quad * 8];
        }
        f32x4 sv[4];
        #pragma unroll
        for (int f = 0; f < 4; ++f) {
            f32x4 s = {};
            s = __builtin_amdgcn_mfma_f32_16x16x32_bf16(kf0[f], qf0, s, 0, 0, 0);
            s = __builtin_amdgcn_mfma_f32_16x16x32_bf16(kf1[f], qf1, s, 0, 0, 0);
            sv[f] = s;
        }

        // scale (+ causal mask only on the diagonal-straddling tiles)
        if (kt * 64 + 63 <= q0 + w * 16) {   // wave-uniform: fully unmasked
            #pragma unroll
            for (int f = 0; f < 4; ++f)
                #pragma unroll
                for (int r = 0; r < 4; ++r) sv[f][r] *= 0.125f;
        } else {
            #pragma unroll
            for (int f = 0; f < 4; ++f) {
                #pragma unroll
                for (int r = 0; r < 4; ++r) {
                    const int kg = kt * 64 + f * 16 + quad * 4 + r;
                    sv[f][r] = (kg <= qg) ? sv[f][r] * 0.125f : -1e30f;
                }
            }
        }

        // online softmax for this lane's query: 16 in-lane values + quads
        float mf[4];
        #pragma unroll
        for (int f = 0; f < 4; ++f)
            mf[f] = fmaxf(fmaxf(sv[f][0], sv[f][1]), fmaxf(sv[f][2], sv[f][3]));
        float mx = fmaxf(fmaxf(mf[0], mf[1]), fmaxf(mf[2], mf[3]));
        mx = fmaxf(mx, __shfl_xor(mx, 16));
        mx = fmaxf(mx, __shfl_xor(mx, 32));
        const float mn = fmaxf(m_run, mx);
        const float al = __expf(m_run - mn);   // <=0 arg; exp(-1e30)=0 first iter
        m_run = mn;
        float sf[4];
        #pragma unroll
        for (int f = 0; f < 4; ++f) {
            #pragma unroll
            for (int r = 0; r < 4; ++r) sv[f][r] = __expf(sv[f][r] - mn);
            sf[f] = (sv[f][0] + sv[f][1]) + (sv[f][2] + sv[f][3]);
        }
        float rs = (sf[0] + sf[1]) + (sf[2] + sf[3]);
        rs += __shfl_xor(rs, 16);
        rs += __shfl_xor(rs, 32);
        l_run = l_run * al + rs;

        // rescale O accumulator (alpha lives at lane quad*4+r for that row)
        #pragma unroll
        for (int r = 0; r < 4; ++r) {
            const float ar = __shfl(al, quad * 4 + r);
            #pragma unroll
            for (int t = 0; t < 4; ++t) o[t][r] *= ar;
        }

        // P: lane holds (query=l15, keys f*16+quad*4+r) -> row-major LDS
        #pragma unroll
        for (int f = 0; f < 4; ++f)
            #pragma unroll
            for (int r = 0; r < 4; ++r)
                Pw[(w * 16 + l15) * VP + f * 16 + quad * 4 + r] = f2bf(sv[f][r]);

        // wave-local: ensure P stores land before frag reads (no block barrier)
        __asm__ volatile("s_waitcnt lgkmcnt(0)" ::: "memory");

        // O += P V   (A=P rows are this wave's own queries)
        #pragma unroll
        for (int s = 0; s < 2; ++s) {
            const bf16x8 pf = *(const bf16x8*)&Pw[(w * 16 + l15) * VP + s * 32 + quad * 8];
            #pragma unroll
            for (int t = 0; t < 4; ++t) {
                const bf16x8 vf = *(const bf16x8*)&Vt[(t * 16 + l15) * VP + s * 32 + quad * 8];
                o[t] = __builtin_amdgcn_mfma_f32_16x16x32_bf16(pf, vf, o[t], 0, 0, 0);
            }
        }
        __syncthreads();   // all waves done reading Vt

        // commit prefetched V tile
        #pragma unroll
        for (int j = 0; j < 8; ++j) {
            Vt[(dc0 * 8 + j) * VP + vkey] = vn0[j];
            Vt[(dc1 * 8 + j) * VP + vkey] = vn1[j];
        }
        __syncthreads();
    }

    const float inv = 1.f / l_run;   // for query l15
    #pragma unroll
    for (int r = 0; r < 4; ++r) {
        const float ir = __shfl(inv, quad * 4 + r);
        const size_t row = (size_t)(b * SEQ + q0 + w * 16 + quad * 4 + r) * D_MODEL + headoff;
        #pragma unroll
        for (int t = 0; t < 4; ++t)
            Og[row + t * 16 + l15] = f2bf(o[t][r] * ir);
    }
}

// ---------------------------------------------------------------------------
// LayerNorm over last dim (1024), one block per row, fp32 in/out (in-place ok).
// ---------------------------------------------------------------------------
__global__ __launch_bounds__(256) void ln_kernel(
    const float* __restrict__ X, const float* __restrict__ g,
    const float* __restrict__ bta, float* __restrict__ out)
{
    __shared__ float r1[4], r2[4];
    const int row = blockIdx.x;
    const int tid = threadIdx.x;
    const float* p = X + (size_t)row * D_MODEL;
    float v[4]; float s1 = 0.f, s2 = 0.f;
    #pragma unroll
    for (int i = 0; i < 4; ++i) { v[i] = p[tid + 256 * i]; s1 += v[i]; s2 += v[i] * v[i]; }
    #pragma unroll
    for (int d = 32; d >= 1; d >>= 1) { s1 += __shfl_xor(s1, d); s2 += __shfl_xor(s2, d); }
    if ((tid & 63) == 0) { r1[tid >> 6] = s1; r2[tid >> 6] = s2; }
    __syncthreads();
    s1 = r1[0] + r1[1] + r1[2] + r1[3];
    s2 = r2[0] + r2[1] + r2[2] + r2[3];
    const float mu  = s1 * (1.f / D_MODEL);
    const float var = s2 * (1.f / D_MODEL) - mu * mu;
    const float rstd = rsqrtf(var + 1e-5f);
    #pragma unroll
    for (int i = 0; i < 4; ++i) {
        const int c = tid + 256 * i;
        out[(size_t)row * D_MODEL + c] = (v[i] - mu) * rstd * g[c] + bta[c];
    }
}

extern "C" void kernel_launch(void* const* d_in, const int* in_sizes, int n_in,
                              void* d_out, int out_size, void* d_ws, size_t ws_size,
                              hipStream_t stream) {
    const float* x     = (const float*)d_in[0];
    const float* Wq    = (const float*)d_in[1];
    const float* bq    = (const float*)d_in[2];
    const float* Wk    = (const float*)d_in[3];
    const float* bk    = (const float*)d_in[4];
    const float* Wv    = (const float*)d_in[5];
    const float* bv    = (const float*)d_in[6];
    const float* Wo    = (const float*)d_in[7];
    const float* bo    = (const float*)d_in[8];
    const float* gamma = (const float*)d_in[9];
    const float* beta  = (const float*)d_in[10];

    const size_t XN = (size_t)MROWS * D_MODEL;      // 4 Mi elements
    const size_t WN = (size_t)D_MODEL * D_MODEL;    // 1 Mi elements
    ushort_t* wsp = (ushort_t*)d_ws;
    ushort_t* xb  = wsp;
    ushort_t* Yq  = wsp + XN;
    ushort_t* Yk  = wsp + 2 * XN;
    ushort_t* Yv  = wsp + 3 * XN;
    ushort_t* Wqb = wsp + 4 * XN;
    ushort_t* Wkb = Wqb + WN;
    ushort_t* Wvb = Wkb + WN;
    ushort_t* Wob = Wvb + WN;
    ushort_t* ctx = xb;                 // overlay: xb dead after QKV gemm
    float*    pre = (float*)d_out;      // fp32 pre-LN lives in d_out; LN in-place

    cvt_kernel<<<dim3(8192), 256, 0, stream>>>(x, Wq, Wk, Wv, Wo, xb, Wqb, Wkb, Wvb, Wob);

    gemm_nt<ushort_t, false><<<dim3(MROWS / 64, D_MODEL / 64, 3), 256, 0, stream>>>(
        xb, Wqb, Wkb, Wvb, bq, bk, bv, nullptr, Yq, Yk, Yv);

    attn_kernel<<<dim3(SEQ / 64, BATCH * NHEADS), 256, 0, stream>>>(Yq, Yk, Yv, ctx);

    gemm_nt<float, true><<<dim3(MROWS / 64, D_MODEL / 64, 1), 256, 0, stream>>>(
        ctx, Wob, Wob, Wob, bo, bo, bo, x, pre, pre, pre);

    ln_kernel<<<dim3(MROWS), 256, 0, stream>>>(pre, gamma, beta, (float*)d_out);
}

// Round 5
// 329.578 us; speedup vs baseline: 1.0226x; 1.0226x over previous
//
#include <hip/hip_runtime.h>
#include <type_traits>

#define D_MODEL 1024
#define NHEADS 16
#define DHEAD 64
#define SEQ 2048
#define BATCH 2
#define MROWS (BATCH*SEQ)   // 4096

typedef unsigned short ushort_t;
using bf16x8 = __attribute__((ext_vector_type(8))) __bf16;
using us4    = __attribute__((ext_vector_type(4))) unsigned short;
using us8    = __attribute__((ext_vector_type(8))) unsigned short;
using f32x4  = __attribute__((ext_vector_type(4))) float;

__device__ __forceinline__ ushort_t f2bf(float f) {
    unsigned int u = __builtin_bit_cast(unsigned int, f);
    u += 0x7FFFu + ((u >> 16) & 1u);
    return (ushort_t)(u >> 16);
}

// ---------------------------------------------------------------------------
// Convert fp32 inputs -> canonical bf16: x (4M) + Wq/Wk/Wv/Wo (1M each) = 8M.
// ---------------------------------------------------------------------------
__global__ __launch_bounds__(256) void cvt_kernel(
    const float* __restrict__ x,
    const float* __restrict__ wq, const float* __restrict__ wk,
    const float* __restrict__ wv, const float* __restrict__ wo,
    ushort_t* __restrict__ xb,
    ushort_t* __restrict__ wqb, ushort_t* __restrict__ wkb,
    ushort_t* __restrict__ wvb, ushort_t* __restrict__ wob)
{
    const size_t XN = (size_t)MROWS * D_MODEL;          // 4 Mi
    const size_t WN = (size_t)D_MODEL * D_MODEL;        // 1 Mi
    size_t i = ((size_t)blockIdx.x * 256 + threadIdx.x) * 4;
    const float* s; ushort_t* d; size_t off;
    if (i < XN) { s = x; d = xb; off = i; }
    else {
        size_t j = i - XN;
        int w = (int)(j / WN);
        off = j - (size_t)w * WN;
        s = (w == 0) ? wq : (w == 1) ? wk : (w == 2) ? wv : wo;
        d = (w == 0) ? wqb : (w == 1) ? wkb : (w == 2) ? wvb : wob;
    }
    const f32x4 v = *(const f32x4*)(s + off);
    us4 o;
    #pragma unroll
    for (int t = 0; t < 4; ++t) o[t] = f2bf(v[t]);
    *(us4*)(d + off) = o;
}

// ---------------------------------------------------------------------------
// NT GEMM: Y[M,1024] = A[M,1024] @ W[1024,1024]^T + bias (+ residual, fp32)
// 64x64 tile per block, 4 waves (2x2), each wave 32x32 via 2x2 mfma 16x16x32.
// ---------------------------------------------------------------------------
template<typename OutT, bool RES>
__global__ __launch_bounds__(256) void gemm_nt(
    const ushort_t* __restrict__ A,
    const ushort_t* __restrict__ W0, const ushort_t* __restrict__ W1, const ushort_t* __restrict__ W2,
    const float* __restrict__ b0, const float* __restrict__ b1, const float* __restrict__ b2,
    const float* __restrict__ res,
    OutT* __restrict__ Y0, OutT* __restrict__ Y1, OutT* __restrict__ Y2)
{
    constexpr int K  = D_MODEL;
    constexpr int BK = 32;
    constexpr int LDP = BK + 8;
    __shared__ ushort_t As[64 * LDP];
    __shared__ ushort_t Ws[64 * LDP];

    const int z = blockIdx.z;
    const ushort_t* W  = (z == 0) ? W0 : (z == 1) ? W1 : W2;
    const float* bias  = (z == 0) ? b0 : (z == 1) ? b1 : b2;
    OutT* Y            = (z == 0) ? Y0 : (z == 1) ? Y1 : Y2;

    const int i0 = blockIdx.x * 64;
    const int j0 = blockIdx.y * 64;
    const int tid  = threadIdx.x;
    const int lane = tid & 63;
    const int w    = tid >> 6;
    const int wm   = (w >> 1) * 32;
    const int wn   = (w & 1) * 32;
    const int l15  = lane & 15;
    const int quad = lane >> 4;

    const int sr = tid >> 2;
    const int sc = (tid & 3) * 8;
    const ushort_t* gA = A + (size_t)(i0 + sr) * K + sc;
    const ushort_t* gW = W + (size_t)(j0 + sr) * K + sc;

    f32x4 acc[2][2] = {};

    for (int k0 = 0; k0 < K; k0 += BK) {
        *(us8*)&As[sr * LDP + sc] = *(const us8*)(gA + k0);
        *(us8*)&Ws[sr * LDP + sc] = *(const us8*)(gW + k0);
        __syncthreads();
        bf16x8 af[2], bfr[2];
        af[0]  = *(const bf16x8*)&As[(wm      + l15) * LDP + quad * 8];
        af[1]  = *(const bf16x8*)&As[(wm + 16 + l15) * LDP + quad * 8];
        bfr[0] = *(const bf16x8*)&Ws[(wn      + l15) * LDP + quad * 8];
        bfr[1] = *(const bf16x8*)&Ws[(wn + 16 + l15) * LDP + quad * 8];
        #pragma unroll
        for (int t = 0; t < 2; ++t)
            #pragma unroll
            for (int u = 0; u < 2; ++u)
                acc[t][u] = __builtin_amdgcn_mfma_f32_16x16x32_bf16(af[t], bfr[u], acc[t][u], 0, 0, 0);
        __syncthreads();
    }

    #pragma unroll
    for (int u = 0; u < 2; ++u) {
        const int col = j0 + wn + u * 16 + l15;
        const float bv = bias[col];
        #pragma unroll
        for (int t = 0; t < 2; ++t) {
            #pragma unroll
            for (int r = 0; r < 4; ++r) {
                const int row = i0 + wm + t * 16 + quad * 4 + r;
                float v = acc[t][u][r] + bv;
                if constexpr (RES) v += res[(size_t)row * D_MODEL + col];
                if constexpr (std::is_same<OutT, float>::value)
                    Y[(size_t)row * D_MODEL + col] = v;
                else
                    Y[(size_t)row * D_MODEL + col] = f2bf(v);
            }
        }
    }
}

// ---------------------------------------------------------------------------
// Flash attention v3 (causal): S^T = K Q^T (softmax in-lane), O^T = V^T P^T
// (alpha/l rescale in-lane). K register ping-pong (tile kt+1 loaded during
// tile kt), V LDS double-buffer, ONE raw barrier per iter (no vmcnt drain).
// ---------------------------------------------------------------------------
#define VP 72

__device__ __forceinline__ void attn_step(
    int kt, int nkt,
    const ushort_t* __restrict__ Kbase, const ushort_t* __restrict__ Vbase,
    bf16x8* kc, bf16x8* kn,
    const bf16x8& qf0, const bf16x8& qf1,
    float& m_run, float& l_run, f32x4 (&o)[4],
    const ushort_t* VtCur, ushort_t* VtNxt, ushort_t* Pw,
    int l15, int quad, int w, int qg, int q0,
    int vkey, int dc0, int dc1)
{
    const int ktn = (kt + 1 < nkt) ? kt + 1 : kt;

    // issue next V tile loads first (so their commit-wait skips the K loads)
    const us8 vn0 = *(const us8*)&Vbase[(size_t)(ktn * 64 + vkey) * D_MODEL + dc0 * 8];
    const us8 vn1 = *(const us8*)&Vbase[(size_t)(ktn * 64 + vkey) * D_MODEL + dc1 * 8];
    // issue next K tile loads (consumed NEXT iteration)
    #pragma unroll
    for (int f = 0; f < 4; ++f) {
        const size_t krow = (size_t)(ktn * 64 + f * 16 + l15) * D_MODEL;
        kn[f]     = *(const bf16x8*)&Kbase[krow + quad * 8];
        kn[4 + f] = *(const bf16x8*)&Kbase[krow + 32 + quad * 8];
    }

    // S^T = K Q^T from registers loaded one iteration ago
    f32x4 sv[4];
    #pragma unroll
    for (int f = 0; f < 4; ++f) {
        f32x4 s = {};
        s = __builtin_amdgcn_mfma_f32_16x16x32_bf16(kc[f],     qf0, s, 0, 0, 0);
        s = __builtin_amdgcn_mfma_f32_16x16x32_bf16(kc[4 + f], qf1, s, 0, 0, 0);
        sv[f] = s;
    }

    // scale (+ causal mask only on diagonal-straddling tiles)
    if (kt * 64 + 63 <= q0 + w * 16) {
        #pragma unroll
        for (int f = 0; f < 4; ++f)
            #pragma unroll
            for (int r = 0; r < 4; ++r) sv[f][r] *= 0.125f;
    } else {
        #pragma unroll
        for (int f = 0; f < 4; ++f) {
            #pragma unroll
            for (int r = 0; r < 4; ++r) {
                const int kg = kt * 64 + f * 16 + quad * 4 + r;
                sv[f][r] = (kg <= qg) ? sv[f][r] * 0.125f : -1e30f;
            }
        }
    }

    // online softmax for this lane's query (l15): 16 in-lane + 2 shfls
    float mf[4];
    #pragma unroll
    for (int f = 0; f < 4; ++f)
        mf[f] = fmaxf(fmaxf(sv[f][0], sv[f][1]), fmaxf(sv[f][2], sv[f][3]));
    float mx = fmaxf(fmaxf(mf[0], mf[1]), fmaxf(mf[2], mf[3]));
    mx = fmaxf(mx, __shfl_xor(mx, 16));
    mx = fmaxf(mx, __shfl_xor(mx, 32));
    const float mn = fmaxf(m_run, mx);
    const float al = __expf(m_run - mn);
    m_run = mn;
    float sf[4];
    #pragma unroll
    for (int f = 0; f < 4; ++f) {
        #pragma unroll
        for (int r = 0; r < 4; ++r) sv[f][r] = __expf(sv[f][r] - mn);
        sf[f] = (sv[f][0] + sv[f][1]) + (sv[f][2] + sv[f][3]);
    }
    float rs = (sf[0] + sf[1]) + (sf[2] + sf[3]);
    rs += __shfl_xor(rs, 16);
    rs += __shfl_xor(rs, 32);
    l_run = l_run * al + rs;

    // rescale O^T accumulator — alpha is in-lane (col = query = l15)
    #pragma unroll
    for (int t = 0; t < 4; ++t)
        #pragma unroll
        for (int r = 0; r < 4; ++r) o[t][r] *= al;

    // P pack: keys f*16+quad*4..+3 contiguous -> one b64 store per f
    #pragma unroll
    for (int f = 0; f < 4; ++f) {
        us4 p;
        #pragma unroll
        for (int r = 0; r < 4; ++r) p[r] = f2bf(sv[f][r]);
        *(us4*)&Pw[(w * 16 + l15) * VP + f * 16 + quad * 4] = p;
    }
    __asm__ volatile("s_waitcnt lgkmcnt(0)" ::: "memory");  // wave-private P

    // O^T += V^T P^T  (A=V^T rows d, B=P rows query) — same LDS reads as PV
    #pragma unroll
    for (int s = 0; s < 2; ++s) {
        const bf16x8 pf = *(const bf16x8*)&Pw[(w * 16 + l15) * VP + s * 32 + quad * 8];
        #pragma unroll
        for (int t = 0; t < 4; ++t) {
            const bf16x8 vf = *(const bf16x8*)&VtCur[(t * 16 + l15) * VP + s * 32 + quad * 8];
            o[t] = __builtin_amdgcn_mfma_f32_16x16x32_bf16(vf, pf, o[t], 0, 0, 0);
        }
    }

    // commit next V tile (vmcnt waits only the vn loads; K stays in flight)
    #pragma unroll
    for (int j = 0; j < 8; ++j) {
        VtNxt[(dc0 * 8 + j) * VP + vkey] = vn0[j];
        VtNxt[(dc1 * 8 + j) * VP + vkey] = vn1[j];
    }
    // raw barrier: drain LDS only — prefetched global loads stay outstanding
    __asm__ volatile("s_waitcnt lgkmcnt(0)\n\ts_barrier" ::: "memory");
}

__global__ __launch_bounds__(256, 3) void attn_kernel(
    const ushort_t* __restrict__ Qg, const ushort_t* __restrict__ Kg,
    const ushort_t* __restrict__ Vg, ushort_t* __restrict__ Og)
{
    __shared__ ushort_t Vt[2][DHEAD * VP];
    __shared__ ushort_t Pw[64 * VP];

    const int bh = blockIdx.y;
    const int b = bh >> 4;
    const int h = bh & 15;
    const int qt = gridDim.x - 1 - blockIdx.x;   // heavy blocks dispatch first
    const int q0 = qt * 64;
    const int tid  = threadIdx.x;
    const int lane = tid & 63;
    const int w    = tid >> 6;
    const int l15  = lane & 15;
    const int quad = lane >> 4;

    const size_t headoff = (size_t)h * DHEAD;
    const int qg = q0 + w * 16 + l15;

    const ushort_t* Kbase = Kg + (size_t)(b * SEQ) * D_MODEL + headoff;
    const ushort_t* Vbase = Vg + (size_t)(b * SEQ) * D_MODEL + headoff;

    const size_t qrow = (size_t)(b * SEQ + qg) * D_MODEL + headoff;
    const bf16x8 qf0 = *(const bf16x8*)&Qg[qrow + quad * 8];
    const bf16x8 qf1 = *(const bf16x8*)&Qg[qrow + 32 + quad * 8];

    float m_run = -1e30f, l_run = 0.f;
    f32x4 o[4] = {};   // O^T: row d=t*16+quad*4+r, col query=l15

    const int nkt = qt + 1;
    const int vkey = tid & 63;
    const int dc0  = tid >> 6;
    const int dc1  = dc0 + 4;

    // preload: K tile 0 -> ka, V tile 0 -> Vt[0]
    bf16x8 ka[8], kb[8];
    #pragma unroll
    for (int f = 0; f < 4; ++f) {
        const size_t krow = (size_t)(f * 16 + l15) * D_MODEL;
        ka[f]     = *(const bf16x8*)&Kbase[krow + quad * 8];
        ka[4 + f] = *(const bf16x8*)&Kbase[krow + 32 + quad * 8];
    }
    {
        const us8 a = *(const us8*)&Vbase[(size_t)vkey * D_MODEL + dc0 * 8];
        const us8 c = *(const us8*)&Vbase[(size_t)vkey * D_MODEL + dc1 * 8];
        #pragma unroll
        for (int j = 0; j < 8; ++j) {
            Vt[0][(dc0 * 8 + j) * VP + vkey] = a[j];
            Vt[0][(dc1 * 8 + j) * VP + vkey] = c[j];
        }
    }
    __syncthreads();

    int kt = 0;
    while (kt < nkt) {
        attn_step(kt, nkt, Kbase, Vbase, ka, kb, qf0, qf1, m_run, l_run, o,
                  Vt[0], Vt[1], Pw, l15, quad, w, qg, q0, vkey, dc0, dc1);
        ++kt;
        if (kt >= nkt) break;
        attn_step(kt, nkt, Kbase, Vbase, kb, ka, qf0, qf1, m_run, l_run, o,
                  Vt[1], Vt[0], Pw, l15, quad, w, qg, q0, vkey, dc0, dc1);
        ++kt;
    }

    // write O^T: lane owns query l15; d = t*16+quad*4+r (r contiguous -> b64)
    const float inv = 1.f / l_run;
    const size_t orow = (size_t)(b * SEQ + q0 + w * 16 + l15) * D_MODEL + headoff;
    #pragma unroll
    for (int t = 0; t < 4; ++t) {
        us4 pk;
        #pragma unroll
        for (int r = 0; r < 4; ++r) pk[r] = f2bf(o[t][r] * inv);
        *(us4*)&Og[orow + t * 16 + quad * 4] = pk;
    }
}

// ---------------------------------------------------------------------------
// LayerNorm over last dim (1024), one block per row, fp32 in/out (in-place ok).
// ---------------------------------------------------------------------------
__global__ __launch_bounds__(256) void ln_kernel(
    const float* __restrict__ X, const float* __restrict__ g,
    const float* __restrict__ bta, float* __restrict__ out)
{
    __shared__ float r1[4], r2[4];
    const int row = blockIdx.x;
    const int tid = threadIdx.x;
    const float* p = X + (size_t)row * D_MODEL;
    float v[4]; float s1 = 0.f, s2 = 0.f;
    #pragma unroll
    for (int i = 0; i < 4; ++i) { v[i] = p[tid + 256 * i]; s1 += v[i]; s2 += v[i] * v[i]; }
    #pragma unroll
    for (int d = 32; d >= 1; d >>= 1) { s1 += __shfl_xor(s1, d); s2 += __shfl_xor(s2, d); }
    if ((tid & 63) == 0) { r1[tid >> 6] = s1; r2[tid >> 6] = s2; }
    __syncthreads();
    s1 = r1[0] + r1[1] + r1[2] + r1[3];
    s2 = r2[0] + r2[1] + r2[2] + r2[3];
    const float mu  = s1 * (1.f / D_MODEL);
    const float var = s2 * (1.f / D_MODEL) - mu * mu;
    const float rstd = rsqrtf(var + 1e-5f);
    #pragma unroll
    for (int i = 0; i < 4; ++i) {
        const int c = tid + 256 * i;
        out[(size_t)row * D_MODEL + c] = (v[i] - mu) * rstd * g[c] + bta[c];
    }
}

extern "C" void kernel_launch(void* const* d_in, const int* in_sizes, int n_in,
                              void* d_out, int out_size, void* d_ws, size_t ws_size,
                              hipStream_t stream) {
    const float* x     = (const float*)d_in[0];
    const float* Wq    = (const float*)d_in[1];
    const float* bq    = (const float*)d_in[2];
    const float* Wk    = (const float*)d_in[3];
    const float* bk    = (const float*)d_in[4];
    const float* Wv    = (const float*)d_in[5];
    const float* bv    = (const float*)d_in[6];
    const float* Wo    = (const float*)d_in[7];
    const float* bo    = (const float*)d_in[8];
    const float* gamma = (const float*)d_in[9];
    const float* beta  = (const float*)d_in[10];

    const size_t XN = (size_t)MROWS * D_MODEL;      // 4 Mi elements
    const size_t WN = (size_t)D_MODEL * D_MODEL;    // 1 Mi elements
    ushort_t* wsp = (ushort_t*)d_ws;
    ushort_t* xb  = wsp;
    ushort_t* Yq  = wsp + XN;
    ushort_t* Yk  = wsp + 2 * XN;
    ushort_t* Yv  = wsp + 3 * XN;
    ushort_t* Wqb = wsp + 4 * XN;
    ushort_t* Wkb = Wqb + WN;
    ushort_t* Wvb = Wkb + WN;
    ushort_t* Wob = Wvb + WN;
    ushort_t* ctx = xb;                 // overlay: xb dead after QKV gemm
    float*    pre = (float*)d_out;      // fp32 pre-LN lives in d_out; LN in-place

    cvt_kernel<<<dim3(8192), 256, 0, stream>>>(x, Wq, Wk, Wv, Wo, xb, Wqb, Wkb, Wvb, Wob);

    gemm_nt<ushort_t, false><<<dim3(MROWS / 64, D_MODEL / 64, 3), 256, 0, stream>>>(
        xb, Wqb, Wkb, Wvb, bq, bk, bv, nullptr, Yq, Yk, Yv);

    attn_kernel<<<dim3(SEQ / 64, BATCH * NHEADS), 256, 0, stream>>>(Yq, Yk, Yv, ctx);

    gemm_nt<float, true><<<dim3(MROWS / 64, D_MODEL / 64, 1), 256, 0, stream>>>(
        ctx, Wob, Wob, Wob, bo, bo, bo, x, pre, pre, pre);

    ln_kernel<<<dim3(MROWS), 256, 0, stream>>>(pre, gamma, beta, (float*)d_out);
}

// Round 7
// 279.814 us; speedup vs baseline: 1.2045x; 1.1778x over previous
//
#include <hip/hip_runtime.h>
#include <type_traits>

#define D_MODEL 1024
#define NHEADS 16
#define DHEAD 64
#define SEQ 2048
#define BATCH 2
#define MROWS (BATCH*SEQ)   // 4096

typedef unsigned short ushort_t;
using bf16x8 = __attribute__((ext_vector_type(8))) __bf16;
using us4    = __attribute__((ext_vector_type(4))) unsigned short;
using us8    = __attribute__((ext_vector_type(8))) unsigned short;
using f32x4  = __attribute__((ext_vector_type(4))) float;

__device__ __forceinline__ ushort_t f2bf(float f) {
    unsigned int u = __builtin_bit_cast(unsigned int, f);
    u += 0x7FFFu + ((u >> 16) & 1u);
    return (ushort_t)(u >> 16);
}

// ---------------------------------------------------------------------------
// Convert fp32 inputs -> canonical bf16: x (4M) + Wq/Wk/Wv/Wo (1M each) = 8M.
// ---------------------------------------------------------------------------
__global__ __launch_bounds__(256) void cvt_kernel(
    const float* __restrict__ x,
    const float* __restrict__ wq, const float* __restrict__ wk,
    const float* __restrict__ wv, const float* __restrict__ wo,
    ushort_t* __restrict__ xb,
    ushort_t* __restrict__ wqb, ushort_t* __restrict__ wkb,
    ushort_t* __restrict__ wvb, ushort_t* __restrict__ wob)
{
    const size_t XN = (size_t)MROWS * D_MODEL;          // 4 Mi
    const size_t WN = (size_t)D_MODEL * D_MODEL;        // 1 Mi
    size_t i = ((size_t)blockIdx.x * 256 + threadIdx.x) * 4;
    const float* s; ushort_t* d; size_t off;
    if (i < XN) { s = x; d = xb; off = i; }
    else {
        size_t j = i - XN;
        int w = (int)(j / WN);
        off = j - (size_t)w * WN;
        s = (w == 0) ? wq : (w == 1) ? wk : (w == 2) ? wv : wo;
        d = (w == 0) ? wqb : (w == 1) ? wkb : (w == 2) ? wvb : wob;
    }
    const f32x4 v = *(const f32x4*)(s + off);
    us4 o;
    #pragma unroll
    for (int t = 0; t < 4; ++t) o[t] = f2bf(v[t]);
    *(us4*)(d + off) = o;
}

// ---------------------------------------------------------------------------
// NT GEMM: Y[M,1024] = A[M,1024] @ W[1024,1024]^T + bias (+ residual, fp32)
// 64x64 tile per block, 4 waves (2x2), each wave 32x32 via 2x2 mfma 16x16x32.
// ---------------------------------------------------------------------------
template<typename OutT, bool RES>
__global__ __launch_bounds__(256) void gemm_nt(
    const ushort_t* __restrict__ A,
    const ushort_t* __restrict__ W0, const ushort_t* __restrict__ W1, const ushort_t* __restrict__ W2,
    const float* __restrict__ b0, const float* __restrict__ b1, const float* __restrict__ b2,
    const float* __restrict__ res,
    OutT* __restrict__ Y0, OutT* __restrict__ Y1, OutT* __restrict__ Y2)
{
    constexpr int K  = D_MODEL;
    constexpr int BK = 32;
    constexpr int LDP = BK + 8;
    __shared__ ushort_t As[64 * LDP];
    __shared__ ushort_t Ws[64 * LDP];

    const int z = blockIdx.z;
    const ushort_t* W  = (z == 0) ? W0 : (z == 1) ? W1 : W2;
    const float* bias  = (z == 0) ? b0 : (z == 1) ? b1 : b2;
    OutT* Y            = (z == 0) ? Y0 : (z == 1) ? Y1 : Y2;

    const int i0 = blockIdx.x * 64;
    const int j0 = blockIdx.y * 64;
    const int tid  = threadIdx.x;
    const int lane = tid & 63;
    const int w    = tid >> 6;
    const int wm   = (w >> 1) * 32;
    const int wn   = (w & 1) * 32;
    const int l15  = lane & 15;
    const int quad = lane >> 4;

    const int sr = tid >> 2;
    const int sc = (tid & 3) * 8;
    const ushort_t* gA = A + (size_t)(i0 + sr) * K + sc;
    const ushort_t* gW = W + (size_t)(j0 + sr) * K + sc;

    f32x4 acc[2][2] = {};

    for (int k0 = 0; k0 < K; k0 += BK) {
        *(us8*)&As[sr * LDP + sc] = *(const us8*)(gA + k0);
        *(us8*)&Ws[sr * LDP + sc] = *(const us8*)(gW + k0);
        __syncthreads();
        bf16x8 af[2], bfr[2];
        af[0]  = *(const bf16x8*)&As[(wm      + l15) * LDP + quad * 8];
        af[1]  = *(const bf16x8*)&As[(wm + 16 + l15) * LDP + quad * 8];
        bfr[0] = *(const bf16x8*)&Ws[(wn      + l15) * LDP + quad * 8];
        bfr[1] = *(const bf16x8*)&Ws[(wn + 16 + l15) * LDP + quad * 8];
        #pragma unroll
        for (int t = 0; t < 2; ++t)
            #pragma unroll
            for (int u = 0; u < 2; ++u)
                acc[t][u] = __builtin_amdgcn_mfma_f32_16x16x32_bf16(af[t], bfr[u], acc[t][u], 0, 0, 0);
        __syncthreads();
    }

    #pragma unroll
    for (int u = 0; u < 2; ++u) {
        const int col = j0 + wn + u * 16 + l15;
        const float bv = bias[col];
        #pragma unroll
        for (int t = 0; t < 2; ++t) {
            #pragma unroll
            for (int r = 0; r < 4; ++r) {
                const int row = i0 + wm + t * 16 + quad * 4 + r;
                float v = acc[t][u][r] + bv;
                if constexpr (RES) v += res[(size_t)row * D_MODEL + col];
                if constexpr (std::is_same<OutT, float>::value)
                    Y[(size_t)row * D_MODEL + col] = v;
                else
                    Y[(size_t)row * D_MODEL + col] = f2bf(v);
            }
        }
    }
}

// ---------------------------------------------------------------------------
// Flash attention v5 (causal): round-5 structure (PASSED) + K staged in LDS.
// S^T = K Q^T (softmax in-lane), O^T = V^T P^T (rescale in-lane).
// K and V double-buffered in LDS, coalesced staging once per block (kills the
// 4x per-wave redundant 2KB-stride K loads). One raw barrier per iteration.
// ---------------------------------------------------------------------------
#define VP 72

__global__ __launch_bounds__(256, 3) void attn_kernel(
    const ushort_t* __restrict__ Qg, const ushort_t* __restrict__ Kg,
    const ushort_t* __restrict__ Vg, ushort_t* __restrict__ Og)
{
    __shared__ ushort_t Kt[2][64 * VP];   // [key][dim]
    __shared__ ushort_t Vt[2][64 * VP];   // [dim][key]  (V transposed)
    __shared__ ushort_t Pw[64 * VP];      // [query][key] (wave-private rows)

    const int bh = blockIdx.y;
    const int b = bh >> 4;
    const int h = bh & 15;
    const int qt = gridDim.x - 1 - blockIdx.x;   // heavy blocks dispatch first
    const int q0 = qt * 64;
    const int tid  = threadIdx.x;
    const int lane = tid & 63;
    const int w    = tid >> 6;
    const int l15  = lane & 15;
    const int quad = lane >> 4;

    const size_t headoff = (size_t)h * DHEAD;
    const int qg = q0 + w * 16 + l15;

    const ushort_t* Kbase = Kg + (size_t)(b * SEQ) * D_MODEL + headoff;
    const ushort_t* Vbase = Vg + (size_t)(b * SEQ) * D_MODEL + headoff;

    const size_t qrow = (size_t)(b * SEQ + qg) * D_MODEL + headoff;
    const bf16x8 qf0 = *(const bf16x8*)&Qg[qrow + quad * 8];
    const bf16x8 qf1 = *(const bf16x8*)&Qg[qrow + 32 + quad * 8];

    float m_run = -1e30f, l_run = 0.f;
    f32x4 o[4] = {};   // O^T: row d=t*16+quad*4+r, col query=l15

    const int nkt = qt + 1;

    // staging maps
    const int krow = tid >> 3;      // 0..31 (+32 second shot) — coalesced K
    const int kb   = tid & 7;       // 16B block within the 128B K row
    const int vkey = tid & 63;      // V transposed staging
    const int dc0  = tid >> 6;      // 0..3
    const int dc1  = dc0 + 4;       // 4..7

    us8 kp0, kp1, vp0, vp1;
    // preload tile 0 -> buf 0
    kp0 = *(const us8*)&Kbase[(size_t)krow * D_MODEL + kb * 8];
    kp1 = *(const us8*)&Kbase[(size_t)(32 + krow) * D_MODEL + kb * 8];
    vp0 = *(const us8*)&Vbase[(size_t)vkey * D_MODEL + dc0 * 8];
    vp1 = *(const us8*)&Vbase[(size_t)vkey * D_MODEL + dc1 * 8];
    *(us8*)&Kt[0][krow * VP + kb * 8]        = kp0;
    *(us8*)&Kt[0][(32 + krow) * VP + kb * 8] = kp1;
    #pragma unroll
    for (int j = 0; j < 8; ++j) {
        Vt[0][(dc0 * 8 + j) * VP + vkey] = vp0[j];
        Vt[0][(dc1 * 8 + j) * VP + vkey] = vp1[j];
    }
    __syncthreads();

    for (int kt = 0; kt < nkt; ++kt) {
        const int cur = kt & 1;
        const int nxt = cur ^ 1;
        const bool pre = (kt + 1 < nkt);
        if (pre) {
            const size_t koff = (size_t)((kt + 1) * 64) * D_MODEL;
            kp0 = *(const us8*)&Kbase[koff + (size_t)krow * D_MODEL + kb * 8];
            kp1 = *(const us8*)&Kbase[koff + (size_t)(32 + krow) * D_MODEL + kb * 8];
            vp0 = *(const us8*)&Vbase[koff + (size_t)vkey * D_MODEL + dc0 * 8];
            vp1 = *(const us8*)&Vbase[koff + (size_t)vkey * D_MODEL + dc1 * 8];
        }

        // S^T = K Q^T : K frags from LDS (staged once per block)
        f32x4 sv[4];
        #pragma unroll
        for (int f = 0; f < 4; ++f) {
            const bf16x8 kf0 = *(const bf16x8*)&Kt[cur][(f * 16 + l15) * VP + quad * 8];
            const bf16x8 kf1 = *(const bf16x8*)&Kt[cur][(f * 16 + l15) * VP + 32 + quad * 8];
            f32x4 s = {};
            s = __builtin_amdgcn_mfma_f32_16x16x32_bf16(kf0, qf0, s, 0, 0, 0);
            s = __builtin_amdgcn_mfma_f32_16x16x32_bf16(kf1, qf1, s, 0, 0, 0);
            sv[f] = s;
        }

        // scale (+ causal mask only on diagonal-straddling tiles)
        if (kt * 64 + 63 <= q0 + w * 16) {
            #pragma unroll
            for (int f = 0; f < 4; ++f)
                #pragma unroll
                for (int r = 0; r < 4; ++r) sv[f][r] *= 0.125f;
        } else {
            #pragma unroll
            for (int f = 0; f < 4; ++f) {
                #pragma unroll
                for (int r = 0; r < 4; ++r) {
                    const int kg = kt * 64 + f * 16 + quad * 4 + r;
                    sv[f][r] = (kg <= qg) ? sv[f][r] * 0.125f : -1e30f;
                }
            }
        }

        // online softmax for this lane's query (l15): 16 in-lane + 2 shfls
        float mf[4];
        #pragma unroll
        for (int f = 0; f < 4; ++f)
            mf[f] = fmaxf(fmaxf(sv[f][0], sv[f][1]), fmaxf(sv[f][2], sv[f][3]));
        float mx = fmaxf(fmaxf(mf[0], mf[1]), fmaxf(mf[2], mf[3]));
        mx = fmaxf(mx, __shfl_xor(mx, 16));
        mx = fmaxf(mx, __shfl_xor(mx, 32));
        const float mn = fmaxf(m_run, mx);
        const float al = __expf(m_run - mn);
        m_run = mn;
        float sf[4];
        #pragma unroll
        for (int f = 0; f < 4; ++f) {
            #pragma unroll
            for (int r = 0; r < 4; ++r) sv[f][r] = __expf(sv[f][r] - mn);
            sf[f] = (sv[f][0] + sv[f][1]) + (sv[f][2] + sv[f][3]);
        }
        float rs = (sf[0] + sf[1]) + (sf[2] + sf[3]);
        rs += __shfl_xor(rs, 16);
        rs += __shfl_xor(rs, 32);
        l_run = l_run * al + rs;

        // rescale O^T accumulator — alpha is in-lane (col = query = l15)
        #pragma unroll
        for (int t = 0; t < 4; ++t)
            #pragma unroll
            for (int r = 0; r < 4; ++r) o[t][r] *= al;

        // P pack: keys f*16+quad*4..+3 contiguous -> one b64 store per f
        #pragma unroll
        for (int f = 0; f < 4; ++f) {
            us4 p;
            #pragma unroll
            for (int r = 0; r < 4; ++r) p[r] = f2bf(sv[f][r]);
            *(us4*)&Pw[(w * 16 + l15) * VP + f * 16 + quad * 4] = p;
        }
        __asm__ volatile("s_waitcnt lgkmcnt(0)" ::: "memory");  // wave-private P

        // O^T += V^T P^T
        #pragma unroll
        for (int s = 0; s < 2; ++s) {
            const bf16x8 pf = *(const bf16x8*)&Pw[(w * 16 + l15) * VP + s * 32 + quad * 8];
            #pragma unroll
            for (int t = 0; t < 4; ++t) {
                const bf16x8 vf = *(const bf16x8*)&Vt[cur][(t * 16 + l15) * VP + s * 32 + quad * 8];
                o[t] = __builtin_amdgcn_mfma_f32_16x16x32_bf16(vf, pf, o[t], 0, 0, 0);
            }
        }

        // commit prefetched tile to the other buffer
        if (pre) {
            *(us8*)&Kt[nxt][krow * VP + kb * 8]        = kp0;
            *(us8*)&Kt[nxt][(32 + krow) * VP + kb * 8] = kp1;
            #pragma unroll
            for (int j = 0; j < 8; ++j) {
                Vt[nxt][(dc0 * 8 + j) * VP + vkey] = vp0[j];
                Vt[nxt][(dc1 * 8 + j) * VP + vkey] = vp1[j];
            }
        }
        // raw barrier: drain LDS only — prefetched global loads stay outstanding
        __asm__ volatile("s_waitcnt lgkmcnt(0)\n\ts_barrier" ::: "memory");
    }

    // write O^T: lane owns query l15; d = t*16+quad*4+r (r contiguous -> b64)
    const float inv = 1.f / l_run;
    const size_t orow = (size_t)(b * SEQ + q0 + w * 16 + l15) * D_MODEL + headoff;
    #pragma unroll
    for (int t = 0; t < 4; ++t) {
        us4 pk;
        #pragma unroll
        for (int r = 0; r < 4; ++r) pk[r] = f2bf(o[t][r] * inv);
        *(us4*)&Og[orow + t * 16 + quad * 4] = pk;
    }
}

// ---------------------------------------------------------------------------
// LayerNorm over last dim (1024), one block per row, fp32 in/out (in-place ok).
// ---------------------------------------------------------------------------
__global__ __launch_bounds__(256) void ln_kernel(
    const float* __restrict__ X, const float* __restrict__ g,
    const float* __restrict__ bta, float* __restrict__ out)
{
    __shared__ float r1[4], r2[4];
    const int row = blockIdx.x;
    const int tid = threadIdx.x;
    const float* p = X + (size_t)row * D_MODEL;
    float v[4]; float s1 = 0.f, s2 = 0.f;
    #pragma unroll
    for (int i = 0; i < 4; ++i) { v[i] = p[tid + 256 * i]; s1 += v[i]; s2 += v[i] * v[i]; }
    #pragma unroll
    for (int d = 32; d >= 1; d >>= 1) { s1 += __shfl_xor(s1, d); s2 += __shfl_xor(s2, d); }
    if ((tid & 63) == 0) { r1[tid >> 6] = s1; r2[tid >> 6] = s2; }
    __syncthreads();
    s1 = r1[0] + r1[1] + r1[2] + r1[3];
    s2 = r2[0] + r2[1] + r2[2] + r2[3];
    const float mu  = s1 * (1.f / D_MODEL);
    const float var = s2 * (1.f / D_MODEL) - mu * mu;
    const float rstd = rsqrtf(var + 1e-5f);
    #pragma unroll
    for (int i = 0; i < 4; ++i) {
        const int c = tid + 256 * i;
        out[(size_t)row * D_MODEL + c] = (v[i] - mu) * rstd * g[c] + bta[c];
    }
}

extern "C" void kernel_launch(void* const* d_in, const int* in_sizes, int n_in,
                              void* d_out, int out_size, void* d_ws, size_t ws_size,
                              hipStream_t stream) {
    const float* x     = (const float*)d_in[0];
    const float* Wq    = (const float*)d_in[1];
    const float* bq    = (const float*)d_in[2];
    const float* Wk    = (const float*)d_in[3];
    const float* bk    = (const float*)d_in[4];
    const float* Wv    = (const float*)d_in[5];
    const float* bv    = (const float*)d_in[6];
    const float* Wo    = (const float*)d_in[7];
    const float* bo    = (const float*)d_in[8];
    const float* gamma = (const float*)d_in[9];
    const float* beta  = (const float*)d_in[10];

    const size_t XN = (size_t)MROWS * D_MODEL;      // 4 Mi elements
    const size_t WN = (size_t)D_MODEL * D_MODEL;    // 1 Mi elements
    ushort_t* wsp = (ushort_t*)d_ws;
    ushort_t* xb  = wsp;
    ushort_t* Yq  = wsp + XN;
    ushort_t* Yk  = wsp + 2 * XN;
    ushort_t* Yv  = wsp + 3 * XN;
    ushort_t* Wqb = wsp + 4 * XN;
    ushort_t* Wkb = Wqb + WN;
    ushort_t* Wvb = Wkb + WN;
    ushort_t* Wob = Wvb + WN;
    ushort_t* ctx = xb;                 // overlay: xb dead after QKV gemm
    float*    pre = (float*)d_out;      // fp32 pre-LN lives in d_out; LN in-place

    cvt_kernel<<<dim3(8192), 256, 0, stream>>>(x, Wq, Wk, Wv, Wo, xb, Wqb, Wkb, Wvb, Wob);

    gemm_nt<ushort_t, false><<<dim3(MROWS / 64, D_MODEL / 64, 3), 256, 0, stream>>>(
        xb, Wqb, Wkb, Wvb, bq, bk, bv, nullptr, Yq, Yk, Yv);

    attn_kernel<<<dim3(SEQ / 64, BATCH * NHEADS), 256, 0, stream>>>(Yq, Yk, Yv, ctx);

    gemm_nt<float, true><<<dim3(MROWS / 64, D_MODEL / 64, 1), 256, 0, stream>>>(
        ctx, Wob, Wob, Wob, bo, bo, bo, x, pre, pre, pre);

    ln_kernel<<<dim3(MROWS), 256, 0, stream>>>(pre, gamma, beta, (float*)d_out);
}

// Round 8
// 262.769 us; speedup vs baseline: 1.2826x; 1.0649x over previous
//
#include <hip/hip_runtime.h>
#include <type_traits>

#define D_MODEL 1024
#define NHEADS 16
#define DHEAD 64
#define SEQ 2048
#define BATCH 2
#define MROWS (BATCH*SEQ)   // 4096

typedef unsigned short ushort_t;
using bf16x8 = __attribute__((ext_vector_type(8))) __bf16;
using us4    = __attribute__((ext_vector_type(4))) unsigned short;
using us8    = __attribute__((ext_vector_type(8))) unsigned short;
using f32x4  = __attribute__((ext_vector_type(4))) float;

__device__ __forceinline__ ushort_t f2bf(float f) {
    unsigned int u = __builtin_bit_cast(unsigned int, f);
    u += 0x7FFFu + ((u >> 16) & 1u);
    return (ushort_t)(u >> 16);
}

// async global->LDS, 16B per lane; LDS dest is wave-uniform base + lane*16
__device__ __forceinline__ void gl2lds(const ushort_t* g, ushort_t* l) {
    __builtin_amdgcn_global_load_lds(
        (const __attribute__((address_space(1))) unsigned int*)g,
        (__attribute__((address_space(3))) unsigned int*)l,
        16, 0, 0);
}

// ---------------------------------------------------------------------------
// Convert fp32 inputs -> canonical bf16: x (4M) + Wq/Wk/Wv/Wo (1M each) = 8M.
// ---------------------------------------------------------------------------
__global__ __launch_bounds__(256) void cvt_kernel(
    const float* __restrict__ x,
    const float* __restrict__ wq, const float* __restrict__ wk,
    const float* __restrict__ wv, const float* __restrict__ wo,
    ushort_t* __restrict__ xb,
    ushort_t* __restrict__ wqb, ushort_t* __restrict__ wkb,
    ushort_t* __restrict__ wvb, ushort_t* __restrict__ wob)
{
    const size_t XN = (size_t)MROWS * D_MODEL;          // 4 Mi
    const size_t WN = (size_t)D_MODEL * D_MODEL;        // 1 Mi
    size_t i = ((size_t)blockIdx.x * 256 + threadIdx.x) * 4;
    const float* s; ushort_t* d; size_t off;
    if (i < XN) { s = x; d = xb; off = i; }
    else {
        size_t j = i - XN;
        int w = (int)(j / WN);
        off = j - (size_t)w * WN;
        s = (w == 0) ? wq : (w == 1) ? wk : (w == 2) ? wv : wo;
        d = (w == 0) ? wqb : (w == 1) ? wkb : (w == 2) ? wvb : wob;
    }
    const f32x4 v = *(const f32x4*)(s + off);
    us4 o;
    #pragma unroll
    for (int t = 0; t < 4; ++t) o[t] = f2bf(v[t]);
    *(us4*)(d + off) = o;
}

// ---------------------------------------------------------------------------
// NT GEMM v2 (m97 structure): Y[M,1024] = A @ W^T + bias (+ residual).
// 128x128 tile, 4 waves each 64x64 (4x4 mfma 16x16x32), BK=32,
// global_load_lds width=16 staging (row-major [128][32] LDS, no pad).
// ---------------------------------------------------------------------------
template<typename OutT, bool RES>
__global__ __launch_bounds__(256, 2) void gemm_nt(
    const ushort_t* __restrict__ A,
    const ushort_t* __restrict__ W0, const ushort_t* __restrict__ W1, const ushort_t* __restrict__ W2,
    const float* __restrict__ b0, const float* __restrict__ b1, const float* __restrict__ b2,
    const float* __restrict__ res,
    OutT* __restrict__ Y0, OutT* __restrict__ Y1, OutT* __restrict__ Y2)
{
    constexpr int K  = D_MODEL;
    constexpr int BK = 32;
    __shared__ ushort_t As[128 * BK];   // 8 KB, row-major [row][k]
    __shared__ ushort_t Ws[128 * BK];   // 8 KB

    const int z = blockIdx.z;
    const ushort_t* W  = (z == 0) ? W0 : (z == 1) ? W1 : W2;
    const float* bias  = (z == 0) ? b0 : (z == 1) ? b1 : b2;
    OutT* Y            = (z == 0) ? Y0 : (z == 1) ? Y1 : Y2;

    const int i0 = blockIdx.x * 128;
    const int j0 = blockIdx.y * 128;
    const int tid  = threadIdx.x;
    const int lane = tid & 63;
    const int w    = tid >> 6;
    const int wm   = (w >> 1) * 64;
    const int wn   = (w & 1) * 64;
    const int l15  = lane & 15;
    const int quad = lane >> 4;

    // staging map: wave w stages chunks {2w, 2w+1} of each matrix.
    // chunk c = rows [c*16, c*16+16) of the 128-row tile; 1 KB per chunk.
    // lane i -> row c*16 + i/4, col (i%4)*8 (16B) == LDS base + i*16.
    const int srow = lane >> 2;
    const int scol = (lane & 3) * 8;
    const int c0 = w * 2, c1 = w * 2 + 1;
    const ushort_t* gA0 = A + (size_t)(i0 + c0 * 16 + srow) * K + scol;
    const ushort_t* gA1 = A + (size_t)(i0 + c1 * 16 + srow) * K + scol;
    const ushort_t* gW0 = W + (size_t)(j0 + c0 * 16 + srow) * K + scol;
    const ushort_t* gW1 = W + (size_t)(j0 + c1 * 16 + srow) * K + scol;
    ushort_t* lA0 = As + c0 * 512;
    ushort_t* lA1 = As + c1 * 512;
    ushort_t* lW0 = Ws + c0 * 512;
    ushort_t* lW1 = Ws + c1 * 512;

    f32x4 acc[4][4] = {};

    for (int k0 = 0; k0 < K; k0 += BK) {
        gl2lds(gA0 + k0, lA0);
        gl2lds(gA1 + k0, lA1);
        gl2lds(gW0 + k0, lW0);
        gl2lds(gW1 + k0, lW1);
        __syncthreads();   // vmcnt drained by compiler before barrier

        bf16x8 af[4], wf[4];
        #pragma unroll
        for (int m = 0; m < 4; ++m)
            af[m] = *(const bf16x8*)&As[(wm + m * 16 + l15) * BK + quad * 8];
        #pragma unroll
        for (int n = 0; n < 4; ++n)
            wf[n] = *(const bf16x8*)&Ws[(wn + n * 16 + l15) * BK + quad * 8];
        #pragma unroll
        for (int m = 0; m < 4; ++m)
            #pragma unroll
            for (int n = 0; n < 4; ++n)
                acc[m][n] = __builtin_amdgcn_mfma_f32_16x16x32_bf16(af[m], wf[n], acc[m][n], 0, 0, 0);
        __syncthreads();
    }

    #pragma unroll
    for (int n = 0; n < 4; ++n) {
        const int col = j0 + wn + n * 16 + l15;
        const float bv = bias[col];
        #pragma unroll
        for (int m = 0; m < 4; ++m) {
            #pragma unroll
            for (int r = 0; r < 4; ++r) {
                const int row = i0 + wm + m * 16 + quad * 4 + r;
                float v = acc[m][n][r] + bv;
                if constexpr (RES) v += res[(size_t)row * D_MODEL + col];
                if constexpr (std::is_same<OutT, float>::value)
                    Y[(size_t)row * D_MODEL + col] = v;
                else
                    Y[(size_t)row * D_MODEL + col] = f2bf(v);
            }
        }
    }
}

// ---------------------------------------------------------------------------
// Flash attention v5 (causal) — unchanged from round 7 (PASSED, 107 us).
// S^T = K Q^T (softmax in-lane), O^T = V^T P^T (rescale in-lane).
// K and V double-buffered in LDS, coalesced staging once per block.
// ---------------------------------------------------------------------------
#define VP 72

__global__ __launch_bounds__(256, 3) void attn_kernel(
    const ushort_t* __restrict__ Qg, const ushort_t* __restrict__ Kg,
    const ushort_t* __restrict__ Vg, ushort_t* __restrict__ Og)
{
    __shared__ ushort_t Kt[2][64 * VP];   // [key][dim]
    __shared__ ushort_t Vt[2][64 * VP];   // [dim][key]  (V transposed)
    __shared__ ushort_t Pw[64 * VP];      // [query][key] (wave-private rows)

    const int bh = blockIdx.y;
    const int b = bh >> 4;
    const int h = bh & 15;
    const int qt = gridDim.x - 1 - blockIdx.x;   // heavy blocks dispatch first
    const int q0 = qt * 64;
    const int tid  = threadIdx.x;
    const int lane = tid & 63;
    const int w    = tid >> 6;
    const int l15  = lane & 15;
    const int quad = lane >> 4;

    const size_t headoff = (size_t)h * DHEAD;
    const int qg = q0 + w * 16 + l15;

    const ushort_t* Kbase = Kg + (size_t)(b * SEQ) * D_MODEL + headoff;
    const ushort_t* Vbase = Vg + (size_t)(b * SEQ) * D_MODEL + headoff;

    const size_t qrow = (size_t)(b * SEQ + qg) * D_MODEL + headoff;
    const bf16x8 qf0 = *(const bf16x8*)&Qg[qrow + quad * 8];
    const bf16x8 qf1 = *(const bf16x8*)&Qg[qrow + 32 + quad * 8];

    float m_run = -1e30f, l_run = 0.f;
    f32x4 o[4] = {};   // O^T: row d=t*16+quad*4+r, col query=l15

    const int nkt = qt + 1;

    const int krow = tid >> 3;
    const int kb   = tid & 7;
    const int vkey = tid & 63;
    const int dc0  = tid >> 6;
    const int dc1  = dc0 + 4;

    us8 kp0, kp1, vp0, vp1;
    kp0 = *(const us8*)&Kbase[(size_t)krow * D_MODEL + kb * 8];
    kp1 = *(const us8*)&Kbase[(size_t)(32 + krow) * D_MODEL + kb * 8];
    vp0 = *(const us8*)&Vbase[(size_t)vkey * D_MODEL + dc0 * 8];
    vp1 = *(const us8*)&Vbase[(size_t)vkey * D_MODEL + dc1 * 8];
    *(us8*)&Kt[0][krow * VP + kb * 8]        = kp0;
    *(us8*)&Kt[0][(32 + krow) * VP + kb * 8] = kp1;
    #pragma unroll
    for (int j = 0; j < 8; ++j) {
        Vt[0][(dc0 * 8 + j) * VP + vkey] = vp0[j];
        Vt[0][(dc1 * 8 + j) * VP + vkey] = vp1[j];
    }
    __syncthreads();

    for (int kt = 0; kt < nkt; ++kt) {
        const int cur = kt & 1;
        const int nxt = cur ^ 1;
        const bool pre = (kt + 1 < nkt);
        if (pre) {
            const size_t koff = (size_t)((kt + 1) * 64) * D_MODEL;
            kp0 = *(const us8*)&Kbase[koff + (size_t)krow * D_MODEL + kb * 8];
            kp1 = *(const us8*)&Kbase[koff + (size_t)(32 + krow) * D_MODEL + kb * 8];
            vp0 = *(const us8*)&Vbase[koff + (size_t)vkey * D_MODEL + dc0 * 8];
            vp1 = *(const us8*)&Vbase[koff + (size_t)vkey * D_MODEL + dc1 * 8];
        }

        f32x4 sv[4];
        #pragma unroll
        for (int f = 0; f < 4; ++f) {
            const bf16x8 kf0 = *(const bf16x8*)&Kt[cur][(f * 16 + l15) * VP + quad * 8];
            const bf16x8 kf1 = *(const bf16x8*)&Kt[cur][(f * 16 + l15) * VP + 32 + quad * 8];
            f32x4 s = {};
            s = __builtin_amdgcn_mfma_f32_16x16x32_bf16(kf0, qf0, s, 0, 0, 0);
            s = __builtin_amdgcn_mfma_f32_16x16x32_bf16(kf1, qf1, s, 0, 0, 0);
            sv[f] = s;
        }

        if (kt * 64 + 63 <= q0 + w * 16) {
            #pragma unroll
            for (int f = 0; f < 4; ++f)
                #pragma unroll
                for (int r = 0; r < 4; ++r) sv[f][r] *= 0.125f;
        } else {
            #pragma unroll
            for (int f = 0; f < 4; ++f) {
                #pragma unroll
                for (int r = 0; r < 4; ++r) {
                    const int kg = kt * 64 + f * 16 + quad * 4 + r;
                    sv[f][r] = (kg <= qg) ? sv[f][r] * 0.125f : -1e30f;
                }
            }
        }

        float mf[4];
        #pragma unroll
        for (int f = 0; f < 4; ++f)
            mf[f] = fmaxf(fmaxf(sv[f][0], sv[f][1]), fmaxf(sv[f][2], sv[f][3]));
        float mx = fmaxf(fmaxf(mf[0], mf[1]), fmaxf(mf[2], mf[3]));
        mx = fmaxf(mx, __shfl_xor(mx, 16));
        mx = fmaxf(mx, __shfl_xor(mx, 32));
        const float mn = fmaxf(m_run, mx);
        const float al = __expf(m_run - mn);
        m_run = mn;
        float sf[4];
        #pragma unroll
        for (int f = 0; f < 4; ++f) {
            #pragma unroll
            for (int r = 0; r < 4; ++r) sv[f][r] = __expf(sv[f][r] - mn);
            sf[f] = (sv[f][0] + sv[f][1]) + (sv[f][2] + sv[f][3]);
        }
        float rs = (sf[0] + sf[1]) + (sf[2] + sf[3]);
        rs += __shfl_xor(rs, 16);
        rs += __shfl_xor(rs, 32);
        l_run = l_run * al + rs;

        #pragma unroll
        for (int t = 0; t < 4; ++t)
            #pragma unroll
            for (int r = 0; r < 4; ++r) o[t][r] *= al;

        #pragma unroll
        for (int f = 0; f < 4; ++f) {
            us4 p;
            #pragma unroll
            for (int r = 0; r < 4; ++r) p[r] = f2bf(sv[f][r]);
            *(us4*)&Pw[(w * 16 + l15) * VP + f * 16 + quad * 4] = p;
        }
        __asm__ volatile("s_waitcnt lgkmcnt(0)" ::: "memory");

        #pragma unroll
        for (int s = 0; s < 2; ++s) {
            const bf16x8 pf = *(const bf16x8*)&Pw[(w * 16 + l15) * VP + s * 32 + quad * 8];
            #pragma unroll
            for (int t = 0; t < 4; ++t) {
                const bf16x8 vf = *(const bf16x8*)&Vt[cur][(t * 16 + l15) * VP + s * 32 + quad * 8];
                o[t] = __builtin_amdgcn_mfma_f32_16x16x32_bf16(vf, pf, o[t], 0, 0, 0);
            }
        }

        if (pre) {
            *(us8*)&Kt[nxt][krow * VP + kb * 8]        = kp0;
            *(us8*)&Kt[nxt][(32 + krow) * VP + kb * 8] = kp1;
            #pragma unroll
            for (int j = 0; j < 8; ++j) {
                Vt[nxt][(dc0 * 8 + j) * VP + vkey] = vp0[j];
                Vt[nxt][(dc1 * 8 + j) * VP + vkey] = vp1[j];
            }
        }
        __asm__ volatile("s_waitcnt lgkmcnt(0)\n\ts_barrier" ::: "memory");
    }

    const float inv = 1.f / l_run;
    const size_t orow = (size_t)(b * SEQ + q0 + w * 16 + l15) * D_MODEL + headoff;
    #pragma unroll
    for (int t = 0; t < 4; ++t) {
        us4 pk;
        #pragma unroll
        for (int r = 0; r < 4; ++r) pk[r] = f2bf(o[t][r] * inv);
        *(us4*)&Og[orow + t * 16 + quad * 4] = pk;
    }
}

// ---------------------------------------------------------------------------
// LayerNorm over last dim (1024), one block per row, fp32 in/out (in-place ok).
// ---------------------------------------------------------------------------
__global__ __launch_bounds__(256) void ln_kernel(
    const float* __restrict__ X, const float* __restrict__ g,
    const float* __restrict__ bta, float* __restrict__ out)
{
    __shared__ float r1[4], r2[4];
    const int row = blockIdx.x;
    const int tid = threadIdx.x;
    const float* p = X + (size_t)row * D_MODEL;
    float v[4]; float s1 = 0.f, s2 = 0.f;
    #pragma unroll
    for (int i = 0; i < 4; ++i) { v[i] = p[tid + 256 * i]; s1 += v[i]; s2 += v[i] * v[i]; }
    #pragma unroll
    for (int d = 32; d >= 1; d >>= 1) { s1 += __shfl_xor(s1, d); s2 += __shfl_xor(s2, d); }
    if ((tid & 63) == 0) { r1[tid >> 6] = s1; r2[tid >> 6] = s2; }
    __syncthreads();
    s1 = r1[0] + r1[1] + r1[2] + r1[3];
    s2 = r2[0] + r2[1] + r2[2] + r2[3];
    const float mu  = s1 * (1.f / D_MODEL);
    const float var = s2 * (1.f / D_MODEL) - mu * mu;
    const float rstd = rsqrtf(var + 1e-5f);
    #pragma unroll
    for (int i = 0; i < 4; ++i) {
        const int c = tid + 256 * i;
        out[(size_t)row * D_MODEL + c] = (v[i] - mu) * rstd * g[c] + bta[c];
    }
}

extern "C" void kernel_launch(void* const* d_in, const int* in_sizes, int n_in,
                              void* d_out, int out_size, void* d_ws, size_t ws_size,
                              hipStream_t stream) {
    const float* x     = (const float*)d_in[0];
    const float* Wq    = (const float*)d_in[1];
    const float* bq    = (const float*)d_in[2];
    const float* Wk    = (const float*)d_in[3];
    const float* bk    = (const float*)d_in[4];
    const float* Wv    = (const float*)d_in[5];
    const float* bv    = (const float*)d_in[6];
    const float* Wo    = (const float*)d_in[7];
    const float* bo    = (const float*)d_in[8];
    const float* gamma = (const float*)d_in[9];
    const float* beta  = (const float*)d_in[10];

    const size_t XN = (size_t)MROWS * D_MODEL;      // 4 Mi elements
    const size_t WN = (size_t)D_MODEL * D_MODEL;    // 1 Mi elements
    ushort_t* wsp = (ushort_t*)d_ws;
    ushort_t* xb  = wsp;
    ushort_t* Yq  = wsp + XN;
    ushort_t* Yk  = wsp + 2 * XN;
    ushort_t* Yv  = wsp + 3 * XN;
    ushort_t* Wqb = wsp + 4 * XN;
    ushort_t* Wkb = Wqb + WN;
    ushort_t* Wvb = Wkb + WN;
    ushort_t* Wob = Wvb + WN;
    ushort_t* ctx = xb;                 // overlay: xb dead after QKV gemm
    float*    pre = (float*)d_out;      // fp32 pre-LN lives in d_out; LN in-place

    cvt_kernel<<<dim3(8192), 256, 0, stream>>>(x, Wq, Wk, Wv, Wo, xb, Wqb, Wkb, Wvb, Wob);

    gemm_nt<ushort_t, false><<<dim3(MROWS / 128, D_MODEL / 128, 3), 256, 0, stream>>>(
        xb, Wqb, Wkb, Wvb, bq, bk, bv, nullptr, Yq, Yk, Yv);

    attn_kernel<<<dim3(SEQ / 64, BATCH * NHEADS), 256, 0, stream>>>(Yq, Yk, Yv, ctx);

    gemm_nt<float, true><<<dim3(MROWS / 128, D_MODEL / 128, 1), 256, 0, stream>>>(
        ctx, Wob, Wob, Wob, bo, bo, bo, x, pre, pre, pre);

    ln_kernel<<<dim3(MROWS), 256, 0, stream>>>(pre, gamma, beta, (float*)d_out);
}

// Round 9
// 222.832 us; speedup vs baseline: 1.5125x; 1.1792x over previous
//
#include <hip/hip_runtime.h>
#include <type_traits>

#define D_MODEL 1024
#define NHEADS 16
#define DHEAD 64
#define SEQ 2048
#define BATCH 2
#define MROWS (BATCH*SEQ)   // 4096
#define NQT (SEQ/64)        // 32 q-tiles per (b,h)

typedef unsigned short ushort_t;
using bf16x8 = __attribute__((ext_vector_type(8))) __bf16;
using us4    = __attribute__((ext_vector_type(4))) unsigned short;
using us8    = __attribute__((ext_vector_type(8))) unsigned short;
using f32x4  = __attribute__((ext_vector_type(4))) float;

__device__ __forceinline__ ushort_t f2bf(float f) {
    unsigned int u = __builtin_bit_cast(unsigned int, f);
    u += 0x7FFFu + ((u >> 16) & 1u);
    return (ushort_t)(u >> 16);
}

// async global->LDS, 16B per lane; LDS dest is wave-uniform base + lane*16
__device__ __forceinline__ void gl2lds(const ushort_t* g, ushort_t* l) {
    __builtin_amdgcn_global_load_lds(
        (const __attribute__((address_space(1))) unsigned int*)g,
        (__attribute__((address_space(3))) unsigned int*)l,
        16, 0, 0);
}

// ---------------------------------------------------------------------------
// Convert fp32 inputs -> canonical bf16: x (4M) + Wq/Wk/Wv/Wo (1M each) = 8M.
// ---------------------------------------------------------------------------
__global__ __launch_bounds__(256) void cvt_kernel(
    const float* __restrict__ x,
    const float* __restrict__ wq, const float* __restrict__ wk,
    const float* __restrict__ wv, const float* __restrict__ wo,
    ushort_t* __restrict__ xb,
    ushort_t* __restrict__ wqb, ushort_t* __restrict__ wkb,
    ushort_t* __restrict__ wvb, ushort_t* __restrict__ wob)
{
    const size_t XN = (size_t)MROWS * D_MODEL;          // 4 Mi
    const size_t WN = (size_t)D_MODEL * D_MODEL;        // 1 Mi
    size_t i = ((size_t)blockIdx.x * 256 + threadIdx.x) * 4;
    const float* s; ushort_t* d; size_t off;
    if (i < XN) { s = x; d = xb; off = i; }
    else {
        size_t j = i - XN;
        int w = (int)(j / WN);
        off = j - (size_t)w * WN;
        s = (w == 0) ? wq : (w == 1) ? wk : (w == 2) ? wv : wo;
        d = (w == 0) ? wqb : (w == 1) ? wkb : (w == 2) ? wvb : wob;
    }
    const f32x4 v = *(const f32x4*)(s + off);
    us4 o;
    #pragma unroll
    for (int t = 0; t < 4; ++t) o[t] = f2bf(v[t]);
    *(us4*)(d + off) = o;
}

// ---------------------------------------------------------------------------
// NT GEMM v2 (m97 structure): Y[M,1024] = A @ W^T + bias (+ residual).
// 128x128 tile, 4 waves each 64x64 (4x4 mfma 16x16x32), BK=32,
// global_load_lds width=16 staging (row-major [128][32] LDS, no pad).
// ---------------------------------------------------------------------------
template<typename OutT, bool RES>
__global__ __launch_bounds__(256, 2) void gemm_nt(
    const ushort_t* __restrict__ A,
    const ushort_t* __restrict__ W0, const ushort_t* __restrict__ W1, const ushort_t* __restrict__ W2,
    const float* __restrict__ b0, const float* __restrict__ b1, const float* __restrict__ b2,
    const float* __restrict__ res,
    OutT* __restrict__ Y0, OutT* __restrict__ Y1, OutT* __restrict__ Y2)
{
    constexpr int K  = D_MODEL;
    constexpr int BK = 32;
    __shared__ ushort_t As[128 * BK];   // 8 KB, row-major [row][k]
    __shared__ ushort_t Ws[128 * BK];   // 8 KB

    const int z = blockIdx.z;
    const ushort_t* W  = (z == 0) ? W0 : (z == 1) ? W1 : W2;
    const float* bias  = (z == 0) ? b0 : (z == 1) ? b1 : b2;
    OutT* Y            = (z == 0) ? Y0 : (z == 1) ? Y1 : Y2;

    const int i0 = blockIdx.x * 128;
    const int j0 = blockIdx.y * 128;
    const int tid  = threadIdx.x;
    const int lane = tid & 63;
    const int w    = tid >> 6;
    const int wm   = (w >> 1) * 64;
    const int wn   = (w & 1) * 64;
    const int l15  = lane & 15;
    const int quad = lane >> 4;

    const int srow = lane >> 2;
    const int scol = (lane & 3) * 8;
    const int c0 = w * 2, c1 = w * 2 + 1;
    const ushort_t* gA0 = A + (size_t)(i0 + c0 * 16 + srow) * K + scol;
    const ushort_t* gA1 = A + (size_t)(i0 + c1 * 16 + srow) * K + scol;
    const ushort_t* gW0 = W + (size_t)(j0 + c0 * 16 + srow) * K + scol;
    const ushort_t* gW1 = W + (size_t)(j0 + c1 * 16 + srow) * K + scol;
    ushort_t* lA0 = As + c0 * 512;
    ushort_t* lA1 = As + c1 * 512;
    ushort_t* lW0 = Ws + c0 * 512;
    ushort_t* lW1 = Ws + c1 * 512;

    f32x4 acc[4][4] = {};

    for (int k0 = 0; k0 < K; k0 += BK) {
        gl2lds(gA0 + k0, lA0);
        gl2lds(gA1 + k0, lA1);
        gl2lds(gW0 + k0, lW0);
        gl2lds(gW1 + k0, lW1);
        __syncthreads();

        bf16x8 af[4], wf[4];
        #pragma unroll
        for (int m = 0; m < 4; ++m)
            af[m] = *(const bf16x8*)&As[(wm + m * 16 + l15) * BK + quad * 8];
        #pragma unroll
        for (int n = 0; n < 4; ++n)
            wf[n] = *(const bf16x8*)&Ws[(wn + n * 16 + l15) * BK + quad * 8];
        #pragma unroll
        for (int m = 0; m < 4; ++m)
            #pragma unroll
            for (int n = 0; n < 4; ++n)
                acc[m][n] = __builtin_amdgcn_mfma_f32_16x16x32_bf16(af[m], wf[n], acc[m][n], 0, 0, 0);
        __syncthreads();
    }

    #pragma unroll
    for (int n = 0; n < 4; ++n) {
        const int col = j0 + wn + n * 16 + l15;
        const float bv = bias[col];
        #pragma unroll
        for (int m = 0; m < 4; ++m) {
            #pragma unroll
            for (int r = 0; r < 4; ++r) {
                const int row = i0 + wm + m * 16 + quad * 4 + r;
                float v = acc[m][n][r] + bv;
                if constexpr (RES) v += res[(size_t)row * D_MODEL + col];
                if constexpr (std::is_same<OutT, float>::value)
                    Y[(size_t)row * D_MODEL + col] = v;
                else
                    Y[(size_t)row * D_MODEL + col] = f2bf(v);
            }
        }
    }
}

// ---------------------------------------------------------------------------
// Flash attention v6 (causal) = round-7 inner code (PASSED) + load balancing:
// each block processes TWO q-tiles sequentially (heavy 31-p, then light p),
// so every block does exactly 33 iterations -> perfect workload packing.
// ---------------------------------------------------------------------------
#define VP 72

__global__ __launch_bounds__(256, 3) void attn_kernel(
    const ushort_t* __restrict__ Qg, const ushort_t* __restrict__ Kg,
    const ushort_t* __restrict__ Vg, ushort_t* __restrict__ Og)
{
    __shared__ ushort_t Kt[2][64 * VP];   // [key][dim]
    __shared__ ushort_t Vt[2][64 * VP];   // [dim][key]  (V transposed)
    __shared__ ushort_t Pw[64 * VP];      // [query][key] (wave-private rows)

    const int bh = blockIdx.y;
    const int b = bh >> 4;
    const int h = bh & 15;
    const int p = blockIdx.x;             // 0..15 (q-tile pair index)
    const int tid  = threadIdx.x;
    const int lane = tid & 63;
    const int w    = tid >> 6;
    const int l15  = lane & 15;
    const int quad = lane >> 4;

    const size_t headoff = (size_t)h * DHEAD;
    const ushort_t* Kbase = Kg + (size_t)(b * SEQ) * D_MODEL + headoff;
    const ushort_t* Vbase = Vg + (size_t)(b * SEQ) * D_MODEL + headoff;

    // staging maps (loop-invariant)
    const int krow = tid >> 3;
    const int kb   = tid & 7;
    const int vkey = tid & 63;
    const int dc0  = tid >> 6;
    const int dc1  = dc0 + 4;

    for (int half = 0; half < 2; ++half) {
        const int qt = half ? p : (NQT - 1 - p);   // heavy tile first
        const int q0 = qt * 64;
        const int qg = q0 + w * 16 + l15;
        const int nkt = qt + 1;

        const size_t qrow = (size_t)(b * SEQ + qg) * D_MODEL + headoff;
        const bf16x8 qf0 = *(const bf16x8*)&Qg[qrow + quad * 8];
        const bf16x8 qf1 = *(const bf16x8*)&Qg[qrow + 32 + quad * 8];

        float m_run = -1e30f, l_run = 0.f;
        f32x4 o[4] = {};   // O^T: row d=t*16+quad*4+r, col query=l15

        us8 kp0, kp1, vp0, vp1;
        kp0 = *(const us8*)&Kbase[(size_t)krow * D_MODEL + kb * 8];
        kp1 = *(const us8*)&Kbase[(size_t)(32 + krow) * D_MODEL + kb * 8];
        vp0 = *(const us8*)&Vbase[(size_t)vkey * D_MODEL + dc0 * 8];
        vp1 = *(const us8*)&Vbase[(size_t)vkey * D_MODEL + dc1 * 8];
        *(us8*)&Kt[0][krow * VP + kb * 8]        = kp0;
        *(us8*)&Kt[0][(32 + krow) * VP + kb * 8] = kp1;
        #pragma unroll
        for (int j = 0; j < 8; ++j) {
            Vt[0][(dc0 * 8 + j) * VP + vkey] = vp0[j];
            Vt[0][(dc1 * 8 + j) * VP + vkey] = vp1[j];
        }
        __syncthreads();

        for (int kt = 0; kt < nkt; ++kt) {
            const int cur = kt & 1;
            const int nxt = cur ^ 1;
            const bool pre = (kt + 1 < nkt);
            if (pre) {
                const size_t koff = (size_t)((kt + 1) * 64) * D_MODEL;
                kp0 = *(const us8*)&Kbase[koff + (size_t)krow * D_MODEL + kb * 8];
                kp1 = *(const us8*)&Kbase[koff + (size_t)(32 + krow) * D_MODEL + kb * 8];
                vp0 = *(const us8*)&Vbase[koff + (size_t)vkey * D_MODEL + dc0 * 8];
                vp1 = *(const us8*)&Vbase[koff + (size_t)vkey * D_MODEL + dc1 * 8];
            }

            f32x4 sv[4];
            #pragma unroll
            for (int f = 0; f < 4; ++f) {
                const bf16x8 kf0 = *(const bf16x8*)&Kt[cur][(f * 16 + l15) * VP + quad * 8];
                const bf16x8 kf1 = *(const bf16x8*)&Kt[cur][(f * 16 + l15) * VP + 32 + quad * 8];
                f32x4 s = {};
                s = __builtin_amdgcn_mfma_f32_16x16x32_bf16(kf0, qf0, s, 0, 0, 0);
                s = __builtin_amdgcn_mfma_f32_16x16x32_bf16(kf1, qf1, s, 0, 0, 0);
                sv[f] = s;
            }

            if (kt * 64 + 63 <= q0 + w * 16) {
                #pragma unroll
                for (int f = 0; f < 4; ++f)
                    #pragma unroll
                    for (int r = 0; r < 4; ++r) sv[f][r] *= 0.125f;
            } else {
                #pragma unroll
                for (int f = 0; f < 4; ++f) {
                    #pragma unroll
                    for (int r = 0; r < 4; ++r) {
                        const int kg = kt * 64 + f * 16 + quad * 4 + r;
                        sv[f][r] = (kg <= qg) ? sv[f][r] * 0.125f : -1e30f;
                    }
                }
            }

            float mf[4];
            #pragma unroll
            for (int f = 0; f < 4; ++f)
                mf[f] = fmaxf(fmaxf(sv[f][0], sv[f][1]), fmaxf(sv[f][2], sv[f][3]));
            float mx = fmaxf(fmaxf(mf[0], mf[1]), fmaxf(mf[2], mf[3]));
            mx = fmaxf(mx, __shfl_xor(mx, 16));
            mx = fmaxf(mx, __shfl_xor(mx, 32));
            const float mn = fmaxf(m_run, mx);
            const float al = __expf(m_run - mn);
            m_run = mn;
            float sf[4];
            #pragma unroll
            for (int f = 0; f < 4; ++f) {
                #pragma unroll
                for (int r = 0; r < 4; ++r) sv[f][r] = __expf(sv[f][r] - mn);
                sf[f] = (sv[f][0] + sv[f][1]) + (sv[f][2] + sv[f][3]);
            }
            float rs = (sf[0] + sf[1]) + (sf[2] + sf[3]);
            rs += __shfl_xor(rs, 16);
            rs += __shfl_xor(rs, 32);
            l_run = l_run * al + rs;

            #pragma unroll
            for (int t = 0; t < 4; ++t)
                #pragma unroll
                for (int r = 0; r < 4; ++r) o[t][r] *= al;

            #pragma unroll
            for (int f = 0; f < 4; ++f) {
                us4 pk;
                #pragma unroll
                for (int r = 0; r < 4; ++r) pk[r] = f2bf(sv[f][r]);
                *(us4*)&Pw[(w * 16 + l15) * VP + f * 16 + quad * 4] = pk;
            }
            __asm__ volatile("s_waitcnt lgkmcnt(0)" ::: "memory");

            #pragma unroll
            for (int s = 0; s < 2; ++s) {
                const bf16x8 pf = *(const bf16x8*)&Pw[(w * 16 + l15) * VP + s * 32 + quad * 8];
                #pragma unroll
                for (int t = 0; t < 4; ++t) {
                    const bf16x8 vf = *(const bf16x8*)&Vt[cur][(t * 16 + l15) * VP + s * 32 + quad * 8];
                    o[t] = __builtin_amdgcn_mfma_f32_16x16x32_bf16(vf, pf, o[t], 0, 0, 0);
                }
            }

            if (pre) {
                *(us8*)&Kt[nxt][krow * VP + kb * 8]        = kp0;
                *(us8*)&Kt[nxt][(32 + krow) * VP + kb * 8] = kp1;
                #pragma unroll
                for (int j = 0; j < 8; ++j) {
                    Vt[nxt][(dc0 * 8 + j) * VP + vkey] = vp0[j];
                    Vt[nxt][(dc1 * 8 + j) * VP + vkey] = vp1[j];
                }
            }
            __asm__ volatile("s_waitcnt lgkmcnt(0)\n\ts_barrier" ::: "memory");
        }

        const float inv = 1.f / l_run;
        const size_t orow = (size_t)(b * SEQ + q0 + w * 16 + l15) * D_MODEL + headoff;
        #pragma unroll
        for (int t = 0; t < 4; ++t) {
            us4 pk;
            #pragma unroll
            for (int r = 0; r < 4; ++r) pk[r] = f2bf(o[t][r] * inv);
            *(us4*)&Og[orow + t * 16 + quad * 4] = pk;
        }
        // last in-loop s_barrier already ensured all waves finished LDS reads,
        // so the next half's preload writes are safe.
    }
}

// ---------------------------------------------------------------------------
// LayerNorm over last dim (1024), one block per row, fp32 in/out (in-place ok).
// ---------------------------------------------------------------------------
__global__ __launch_bounds__(256) void ln_kernel(
    const float* __restrict__ X, const float* __restrict__ g,
    const float* __restrict__ bta, float* __restrict__ out)
{
    __shared__ float r1[4], r2[4];
    const int row = blockIdx.x;
    const int tid = threadIdx.x;
    const float* p = X + (size_t)row * D_MODEL;
    float v[4]; float s1 = 0.f, s2 = 0.f;
    #pragma unroll
    for (int i = 0; i < 4; ++i) { v[i] = p[tid + 256 * i]; s1 += v[i]; s2 += v[i] * v[i]; }
    #pragma unroll
    for (int d = 32; d >= 1; d >>= 1) { s1 += __shfl_xor(s1, d); s2 += __shfl_xor(s2, d); }
    if ((tid & 63) == 0) { r1[tid >> 6] = s1; r2[tid >> 6] = s2; }
    __syncthreads();
    s1 = r1[0] + r1[1] + r1[2] + r1[3];
    s2 = r2[0] + r2[1] + r2[2] + r2[3];
    const float mu  = s1 * (1.f / D_MODEL);
    const float var = s2 * (1.f / D_MODEL) - mu * mu;
    const float rstd = rsqrtf(var + 1e-5f);
    #pragma unroll
    for (int i = 0; i < 4; ++i) {
        const int c = tid + 256 * i;
        out[(size_t)row * D_MODEL + c] = (v[i] - mu) * rstd * g[c] + bta[c];
    }
}

extern "C" void kernel_launch(void* const* d_in, const int* in_sizes, int n_in,
                              void* d_out, int out_size, void* d_ws, size_t ws_size,
                              hipStream_t stream) {
    const float* x     = (const float*)d_in[0];
    const float* Wq    = (const float*)d_in[1];
    const float* bq    = (const float*)d_in[2];
    const float* Wk    = (const float*)d_in[3];
    const float* bk    = (const float*)d_in[4];
    const float* Wv    = (const float*)d_in[5];
    const float* bv    = (const float*)d_in[6];
    const float* Wo    = (const float*)d_in[7];
    const float* bo    = (const float*)d_in[8];
    const float* gamma = (const float*)d_in[9];
    const float* beta  = (const float*)d_in[10];

    const size_t XN = (size_t)MROWS * D_MODEL;      // 4 Mi elements
    const size_t WN = (size_t)D_MODEL * D_MODEL;    // 1 Mi elements
    ushort_t* wsp = (ushort_t*)d_ws;
    ushort_t* xb  = wsp;
    ushort_t* Yq  = wsp + XN;
    ushort_t* Yk  = wsp + 2 * XN;
    ushort_t* Yv  = wsp + 3 * XN;
    ushort_t* Wqb = wsp + 4 * XN;
    ushort_t* Wkb = Wqb + WN;
    ushort_t* Wvb = Wkb + WN;
    ushort_t* Wob = Wvb + WN;
    ushort_t* ctx = xb;                 // overlay: xb dead after QKV gemm
    float*    pre = (float*)d_out;      // fp32 pre-LN lives in d_out; LN in-place

    cvt_kernel<<<dim3(8192), 256, 0, stream>>>(x, Wq, Wk, Wv, Wo, xb, Wqb, Wkb, Wvb, Wob);

    gemm_nt<ushort_t, false><<<dim3(MROWS / 128, D_MODEL / 128, 3), 256, 0, stream>>>(
        xb, Wqb, Wkb, Wvb, bq, bk, bv, nullptr, Yq, Yk, Yv);

    attn_kernel<<<dim3(SEQ / 128, BATCH * NHEADS), 256, 0, stream>>>(Yq, Yk, Yv, ctx);

    gemm_nt<float, true><<<dim3(MROWS / 128, D_MODEL / 128, 1), 256, 0, stream>>>(
        ctx, Wob, Wob, Wob, bo, bo, bo, x, pre, pre, pre);

    ln_kernel<<<dim3(MROWS), 256, 0, stream>>>(pre, gamma, beta, (float*)d_out);
}

// Round 10
// 220.419 us; speedup vs baseline: 1.5291x; 1.0109x over previous
//
#include <hip/hip_runtime.h>
#include <type_traits>

#define D_MODEL 1024
#define NHEADS 16
#define DHEAD 64
#define SEQ 2048
#define BATCH 2
#define MROWS (BATCH*SEQ)   // 4096
#define NQT (SEQ/64)        // 32 q-tiles per (b,h)

typedef unsigned short ushort_t;
using bf16x8 = __attribute__((ext_vector_type(8))) __bf16;
using us4    = __attribute__((ext_vector_type(4))) unsigned short;
using us8    = __attribute__((ext_vector_type(8))) unsigned short;
using f32x4  = __attribute__((ext_vector_type(4))) float;

__device__ __forceinline__ ushort_t f2bf(float f) {
    unsigned int u = __builtin_bit_cast(unsigned int, f);
    u += 0x7FFFu + ((u >> 16) & 1u);
    return (ushort_t)(u >> 16);
}

// async global->LDS, 16B per lane; LDS dest is wave-uniform base + lane*16
__device__ __forceinline__ void gl2lds(const ushort_t* g, ushort_t* l) {
    __builtin_amdgcn_global_load_lds(
        (const __attribute__((address_space(1))) unsigned int*)g,
        (__attribute__((address_space(3))) unsigned int*)l,
        16, 0, 0);
}

// ---------------------------------------------------------------------------
// Convert fp32 inputs -> canonical bf16: x (4M) + Wq/Wk/Wv/Wo (1M each) = 8M.
// ---------------------------------------------------------------------------
__global__ __launch_bounds__(256) void cvt_kernel(
    const float* __restrict__ x,
    const float* __restrict__ wq, const float* __restrict__ wk,
    const float* __restrict__ wv, const float* __restrict__ wo,
    ushort_t* __restrict__ xb,
    ushort_t* __restrict__ wqb, ushort_t* __restrict__ wkb,
    ushort_t* __restrict__ wvb, ushort_t* __restrict__ wob)
{
    const size_t XN = (size_t)MROWS * D_MODEL;          // 4 Mi
    const size_t WN = (size_t)D_MODEL * D_MODEL;        // 1 Mi
    size_t i = ((size_t)blockIdx.x * 256 + threadIdx.x) * 4;
    const float* s; ushort_t* d; size_t off;
    if (i < XN) { s = x; d = xb; off = i; }
    else {
        size_t j = i - XN;
        int w = (int)(j / WN);
        off = j - (size_t)w * WN;
        s = (w == 0) ? wq : (w == 1) ? wk : (w == 2) ? wv : wo;
        d = (w == 0) ? wqb : (w == 1) ? wkb : (w == 2) ? wvb : wob;
    }
    const f32x4 v = *(const f32x4*)(s + off);
    us4 o;
    #pragma unroll
    for (int t = 0; t < 4; ++t) o[t] = f2bf(v[t]);
    *(us4*)(d + off) = o;
}

// ---------------------------------------------------------------------------
// NT GEMM v2 (m97 structure): Y[M,1024] = A @ W^T + bias (+ residual).
// 128x128 tile, 4 waves each 64x64 (4x4 mfma 16x16x32), BK=32,
// global_load_lds width=16 staging. launch_bounds(256,3): cap VGPR ~170 so
// 3 blocks/CU co-reside (m97: 164 VGPR / 12 waves per CU).
// ---------------------------------------------------------------------------
template<typename OutT, bool RES>
__global__ __launch_bounds__(256, 3) void gemm_nt(
    const ushort_t* __restrict__ A,
    const ushort_t* __restrict__ W0, const ushort_t* __restrict__ W1, const ushort_t* __restrict__ W2,
    const float* __restrict__ b0, const float* __restrict__ b1, const float* __restrict__ b2,
    const float* __restrict__ res,
    OutT* __restrict__ Y0, OutT* __restrict__ Y1, OutT* __restrict__ Y2)
{
    constexpr int K  = D_MODEL;
    constexpr int BK = 32;
    __shared__ ushort_t As[128 * BK];   // 8 KB, row-major [row][k]
    __shared__ ushort_t Ws[128 * BK];   // 8 KB

    const int z = blockIdx.z;
    const ushort_t* W  = (z == 0) ? W0 : (z == 1) ? W1 : W2;
    const float* bias  = (z == 0) ? b0 : (z == 1) ? b1 : b2;
    OutT* Y            = (z == 0) ? Y0 : (z == 1) ? Y1 : Y2;

    const int i0 = blockIdx.x * 128;
    const int j0 = blockIdx.y * 128;
    const int tid  = threadIdx.x;
    const int lane = tid & 63;
    const int w    = tid >> 6;
    const int wm   = (w >> 1) * 64;
    const int wn   = (w & 1) * 64;
    const int l15  = lane & 15;
    const int quad = lane >> 4;

    const int srow = lane >> 2;
    const int scol = (lane & 3) * 8;
    const int c0 = w * 2, c1 = w * 2 + 1;
    const ushort_t* gA0 = A + (size_t)(i0 + c0 * 16 + srow) * K + scol;
    const ushort_t* gA1 = A + (size_t)(i0 + c1 * 16 + srow) * K + scol;
    const ushort_t* gW0 = W + (size_t)(j0 + c0 * 16 + srow) * K + scol;
    const ushort_t* gW1 = W + (size_t)(j0 + c1 * 16 + srow) * K + scol;
    ushort_t* lA0 = As + c0 * 512;
    ushort_t* lA1 = As + c1 * 512;
    ushort_t* lW0 = Ws + c0 * 512;
    ushort_t* lW1 = Ws + c1 * 512;

    f32x4 acc[4][4] = {};

    for (int k0 = 0; k0 < K; k0 += BK) {
        gl2lds(gA0 + k0, lA0);
        gl2lds(gA1 + k0, lA1);
        gl2lds(gW0 + k0, lW0);
        gl2lds(gW1 + k0, lW1);
        __syncthreads();

        bf16x8 af[4], wf[4];
        #pragma unroll
        for (int m = 0; m < 4; ++m)
            af[m] = *(const bf16x8*)&As[(wm + m * 16 + l15) * BK + quad * 8];
        #pragma unroll
        for (int n = 0; n < 4; ++n)
            wf[n] = *(const bf16x8*)&Ws[(wn + n * 16 + l15) * BK + quad * 8];
        #pragma unroll
        for (int m = 0; m < 4; ++m)
            #pragma unroll
            for (int n = 0; n < 4; ++n)
                acc[m][n] = __builtin_amdgcn_mfma_f32_16x16x32_bf16(af[m], wf[n], acc[m][n], 0, 0, 0);
        __syncthreads();
    }

    #pragma unroll
    for (int n = 0; n < 4; ++n) {
        const int col = j0 + wn + n * 16 + l15;
        const float bv = bias[col];
        #pragma unroll
        for (int m = 0; m < 4; ++m) {
            #pragma unroll
            for (int r = 0; r < 4; ++r) {
                const int row = i0 + wm + m * 16 + quad * 4 + r;
                float v = acc[m][n][r] + bv;
                if constexpr (RES) v += res[(size_t)row * D_MODEL + col];
                if constexpr (std::is_same<OutT, float>::value)
                    Y[(size_t)row * D_MODEL + col] = v;
                else
                    Y[(size_t)row * D_MODEL + col] = f2bf(v);
            }
        }
    }
}

// ---------------------------------------------------------------------------
// Flash attention v7 (causal) = v6 (paired q-tiles, PASSED) + l-via-MFMA:
// an all-ones A-fragment accumulates row-sums of P into o4 (rescaled by the
// same alpha as O), so l needs no per-iter shuffle reduction and 1/l is
// in-lane at the end.
// ---------------------------------------------------------------------------
#define VP 72

__global__ __launch_bounds__(256, 3) void attn_kernel(
    const ushort_t* __restrict__ Qg, const ushort_t* __restrict__ Kg,
    const ushort_t* __restrict__ Vg, ushort_t* __restrict__ Og)
{
    __shared__ ushort_t Kt[2][64 * VP];   // [key][dim]
    __shared__ ushort_t Vt[2][64 * VP];   // [dim][key]  (V transposed)
    __shared__ ushort_t Pw[64 * VP];      // [query][key] (wave-private rows)
    __shared__ ushort_t OnesR[16 * VP];   // constant 1.0 region for l-MFMA

    const int bh = blockIdx.y;
    const int b = bh >> 4;
    const int h = bh & 15;
    const int p = blockIdx.x;             // 0..15 (q-tile pair index)
    const int tid  = threadIdx.x;
    const int lane = tid & 63;
    const int w    = tid >> 6;
    const int l15  = lane & 15;
    const int quad = lane >> 4;

    const size_t headoff = (size_t)h * DHEAD;
    const ushort_t* Kbase = Kg + (size_t)(b * SEQ) * D_MODEL + headoff;
    const ushort_t* Vbase = Vg + (size_t)(b * SEQ) * D_MODEL + headoff;

    // staging maps (loop-invariant)
    const int krow = tid >> 3;
    const int kb   = tid & 7;
    const int vkey = tid & 63;
    const int dc0  = tid >> 6;
    const int dc1  = dc0 + 4;

    // init ones region (before the first barrier below)
    for (int i = tid; i < 16 * VP; i += 256) OnesR[i] = 0x3F80;  // bf16 1.0

    bf16x8 onesf[2];
    bool onesLoaded = false;

    for (int half = 0; half < 2; ++half) {
        const int qt = half ? p : (NQT - 1 - p);   // heavy tile first
        const int q0 = qt * 64;
        const int qg = q0 + w * 16 + l15;
        const int nkt = qt + 1;

        const size_t qrow = (size_t)(b * SEQ + qg) * D_MODEL + headoff;
        const bf16x8 qf0 = *(const bf16x8*)&Qg[qrow + quad * 8];
        const bf16x8 qf1 = *(const bf16x8*)&Qg[qrow + 32 + quad * 8];

        float m_run = -1e30f;
        f32x4 o[4] = {};   // O^T: row d=t*16+quad*4+r, col query=l15
        f32x4 o4 = {};     // l accumulator (every reg = running l of query l15)

        us8 kp0, kp1, vp0, vp1;
        kp0 = *(const us8*)&Kbase[(size_t)krow * D_MODEL + kb * 8];
        kp1 = *(const us8*)&Kbase[(size_t)(32 + krow) * D_MODEL + kb * 8];
        vp0 = *(const us8*)&Vbase[(size_t)vkey * D_MODEL + dc0 * 8];
        vp1 = *(const us8*)&Vbase[(size_t)vkey * D_MODEL + dc1 * 8];
        *(us8*)&Kt[0][krow * VP + kb * 8]        = kp0;
        *(us8*)&Kt[0][(32 + krow) * VP + kb * 8] = kp1;
        #pragma unroll
        for (int j = 0; j < 8; ++j) {
            Vt[0][(dc0 * 8 + j) * VP + vkey] = vp0[j];
            Vt[0][(dc1 * 8 + j) * VP + vkey] = vp1[j];
        }
        __syncthreads();

        if (!onesLoaded) {   // constant; load once after the barrier
            onesf[0] = *(const bf16x8*)&OnesR[l15 * VP + quad * 8];
            onesf[1] = *(const bf16x8*)&OnesR[l15 * VP + 32 + quad * 8];
            onesLoaded = true;
        }

        for (int kt = 0; kt < nkt; ++kt) {
            const int cur = kt & 1;
            const int nxt = cur ^ 1;
            const bool pre = (kt + 1 < nkt);
            if (pre) {
                const size_t koff = (size_t)((kt + 1) * 64) * D_MODEL;
                kp0 = *(const us8*)&Kbase[koff + (size_t)krow * D_MODEL + kb * 8];
                kp1 = *(const us8*)&Kbase[koff + (size_t)(32 + krow) * D_MODEL + kb * 8];
                vp0 = *(const us8*)&Vbase[koff + (size_t)vkey * D_MODEL + dc0 * 8];
                vp1 = *(const us8*)&Vbase[koff + (size_t)vkey * D_MODEL + dc1 * 8];
            }

            f32x4 sv[4];
            #pragma unroll
            for (int f = 0; f < 4; ++f) {
                const bf16x8 kf0 = *(const bf16x8*)&Kt[cur][(f * 16 + l15) * VP + quad * 8];
                const bf16x8 kf1 = *(const bf16x8*)&Kt[cur][(f * 16 + l15) * VP + 32 + quad * 8];
                f32x4 s = {};
                s = __builtin_amdgcn_mfma_f32_16x16x32_bf16(kf0, qf0, s, 0, 0, 0);
                s = __builtin_amdgcn_mfma_f32_16x16x32_bf16(kf1, qf1, s, 0, 0, 0);
                sv[f] = s;
            }

            if (kt * 64 + 63 <= q0 + w * 16) {
                #pragma unroll
                for (int f = 0; f < 4; ++f)
                    #pragma unroll
                    for (int r = 0; r < 4; ++r) sv[f][r] *= 0.125f;
            } else {
                #pragma unroll
                for (int f = 0; f < 4; ++f) {
                    #pragma unroll
                    for (int r = 0; r < 4; ++r) {
                        const int kg = kt * 64 + f * 16 + quad * 4 + r;
                        sv[f][r] = (kg <= qg) ? sv[f][r] * 0.125f : -1e30f;
                    }
                }
            }

            float mf[4];
            #pragma unroll
            for (int f = 0; f < 4; ++f)
                mf[f] = fmaxf(fmaxf(sv[f][0], sv[f][1]), fmaxf(sv[f][2], sv[f][3]));
            float mx = fmaxf(fmaxf(mf[0], mf[1]), fmaxf(mf[2], mf[3]));
            mx = fmaxf(mx, __shfl_xor(mx, 16));
            mx = fmaxf(mx, __shfl_xor(mx, 32));
            const float mn = fmaxf(m_run, mx);
            const float al = __expf(m_run - mn);
            m_run = mn;
            #pragma unroll
            for (int f = 0; f < 4; ++f)
                #pragma unroll
                for (int r = 0; r < 4; ++r) sv[f][r] = __expf(sv[f][r] - mn);

            #pragma unroll
            for (int t = 0; t < 4; ++t)
                #pragma unroll
                for (int r = 0; r < 4; ++r) o[t][r] *= al;
            #pragma unroll
            for (int r = 0; r < 4; ++r) o4[r] *= al;

            #pragma unroll
            for (int f = 0; f < 4; ++f) {
                us4 pk;
                #pragma unroll
                for (int r = 0; r < 4; ++r) pk[r] = f2bf(sv[f][r]);
                *(us4*)&Pw[(w * 16 + l15) * VP + f * 16 + quad * 4] = pk;
            }
            __asm__ volatile("s_waitcnt lgkmcnt(0)" ::: "memory");

            #pragma unroll
            for (int s = 0; s < 2; ++s) {
                const bf16x8 pf = *(const bf16x8*)&Pw[(w * 16 + l15) * VP + s * 32 + quad * 8];
                #pragma unroll
                for (int t = 0; t < 4; ++t) {
                    const bf16x8 vf = *(const bf16x8*)&Vt[cur][(t * 16 + l15) * VP + s * 32 + quad * 8];
                    o[t] = __builtin_amdgcn_mfma_f32_16x16x32_bf16(vf, pf, o[t], 0, 0, 0);
                }
                // l-row: A = ones -> every output row = sum_k P[k][query]
                o4 = __builtin_amdgcn_mfma_f32_16x16x32_bf16(onesf[s], pf, o4, 0, 0, 0);
            }

            if (pre) {
                *(us8*)&Kt[nxt][krow * VP + kb * 8]        = kp0;
                *(us8*)&Kt[nxt][(32 + krow) * VP + kb * 8] = kp1;
                #pragma unroll
                for (int j = 0; j < 8; ++j) {
                    Vt[nxt][(dc0 * 8 + j) * VP + vkey] = vp0[j];
                    Vt[nxt][(dc1 * 8 + j) * VP + vkey] = vp1[j];
                }
            }
            __asm__ volatile("s_waitcnt lgkmcnt(0)\n\ts_barrier" ::: "memory");
        }

        const float inv = 1.f / o4[0];   // l for query l15, in-lane
        const size_t orow = (size_t)(b * SEQ + q0 + w * 16 + l15) * D_MODEL + headoff;
        #pragma unroll
        for (int t = 0; t < 4; ++t) {
            us4 pk;
            #pragma unroll
            for (int r = 0; r < 4; ++r) pk[r] = f2bf(o[t][r] * inv);
            *(us4*)&Og[orow + t * 16 + quad * 4] = pk;
        }
    }
}

// ---------------------------------------------------------------------------
// LayerNorm over last dim (1024), one block per row, fp32 in/out (in-place ok).
// ---------------------------------------------------------------------------
__global__ __launch_bounds__(256) void ln_kernel(
    const float* __restrict__ X, const float* __restrict__ g,
    const float* __restrict__ bta, float* __restrict__ out)
{
    __shared__ float r1[4], r2[4];
    const int row = blockIdx.x;
    const int tid = threadIdx.x;
    const float* p = X + (size_t)row * D_MODEL;
    float v[4]; float s1 = 0.f, s2 = 0.f;
    #pragma unroll
    for (int i = 0; i < 4; ++i) { v[i] = p[tid + 256 * i]; s1 += v[i]; s2 += v[i] * v[i]; }
    #pragma unroll
    for (int d = 32; d >= 1; d >>= 1) { s1 += __shfl_xor(s1, d); s2 += __shfl_xor(s2, d); }
    if ((tid & 63) == 0) { r1[tid >> 6] = s1; r2[tid >> 6] = s2; }
    __syncthreads();
    s1 = r1[0] + r1[1] + r1[2] + r1[3];
    s2 = r2[0] + r2[1] + r2[2] + r2[3];
    const float mu  = s1 * (1.f / D_MODEL);
    const float var = s2 * (1.f / D_MODEL) - mu * mu;
    const float rstd = rsqrtf(var + 1e-5f);
    #pragma unroll
    for (int i = 0; i < 4; ++i) {
        const int c = tid + 256 * i;
        out[(size_t)row * D_MODEL + c] = (v[i] - mu) * rstd * g[c] + bta[c];
    }
}

extern "C" void kernel_launch(void* const* d_in, const int* in_sizes, int n_in,
                              void* d_out, int out_size, void* d_ws, size_t ws_size,
                              hipStream_t stream) {
    const float* x     = (const float*)d_in[0];
    const float* Wq    = (const float*)d_in[1];
    const float* bq    = (const float*)d_in[2];
    const float* Wk    = (const float*)d_in[3];
    const float* bk    = (const float*)d_in[4];
    const float* Wv    = (const float*)d_in[5];
    const float* bv    = (const float*)d_in[6];
    const float* Wo    = (const float*)d_in[7];
    const float* bo    = (const float*)d_in[8];
    const float* gamma = (const float*)d_in[9];
    const float* beta  = (const float*)d_in[10];

    const size_t XN = (size_t)MROWS * D_MODEL;      // 4 Mi elements
    const size_t WN = (size_t)D_MODEL * D_MODEL;    // 1 Mi elements
    ushort_t* wsp = (ushort_t*)d_ws;
    ushort_t* xb  = wsp;
    ushort_t* Yq  = wsp + XN;
    ushort_t* Yk  = wsp + 2 * XN;
    ushort_t* Yv  = wsp + 3 * XN;
    ushort_t* Wqb = wsp + 4 * XN;
    ushort_t* Wkb = Wqb + WN;
    ushort_t* Wvb = Wkb + WN;
    ushort_t* Wob = Wvb + WN;
    ushort_t* ctx = xb;                 // overlay: xb dead after QKV gemm
    float*    pre = (float*)d_out;      // fp32 pre-LN lives in d_out; LN in-place

    cvt_kernel<<<dim3(8192), 256, 0, stream>>>(x, Wq, Wk, Wv, Wo, xb, Wqb, Wkb, Wvb, Wob);

    gemm_nt<ushort_t, false><<<dim3(MROWS / 128, D_MODEL / 128, 3), 256, 0, stream>>>(
        xb, Wqb, Wkb, Wvb, bq, bk, bv, nullptr, Yq, Yk, Yv);

    attn_kernel<<<dim3(SEQ / 128, BATCH * NHEADS), 256, 0, stream>>>(Yq, Yk, Yv, ctx);

    gemm_nt<float, true><<<dim3(MROWS / 128, D_MODEL / 128, 1), 256, 0, stream>>>(
        ctx, Wob, Wob, Wob, bo, bo, bo, x, pre, pre, pre);

    ln_kernel<<<dim3(MROWS), 256, 0, stream>>>(pre, gamma, beta, (float*)d_out);
}